// Round 1
// baseline (4283.562 us; speedup 1.0000x reference)
//
#include <hip/hip_runtime.h>
#include <cstddef>
#include <cstdint>

static __device__ __forceinline__ float leaky(float x){ return x >= 0.f ? x : 0.2f*x; }

// ---------------- CSR build ----------------
__global__ void k_init_deg(int* __restrict__ deg, int N){
  int i = blockIdx.x*256 + threadIdx.x;
  if (i < N) deg[i] = 1;                      // self-loop
}
__global__ void k_count(const int* __restrict__ dst, int E, int* __restrict__ deg){
  int e = blockIdx.x*256 + threadIdx.x;
  if (e < E) atomicAdd(&deg[dst[e]], 1);
}
__global__ __launch_bounds__(1024) void k_scan(const int* __restrict__ deg, int* __restrict__ off, int N){
  __shared__ int part[1024];
  int t = threadIdx.x;
  int chunk = (N + 1023) >> 10;
  int b = t*chunk;
  int e = b + chunk; if (e > N) e = N;
  int s = 0;
  for (int i=b; i<e; i++) s += deg[i];
  part[t] = s;
  __syncthreads();
  for (int o=1; o<1024; o<<=1){
    int v = (t >= o) ? part[t-o] : 0;
    __syncthreads();
    part[t] += v;
    __syncthreads();
  }
  int base = (t==0) ? 0 : part[t-1];
  for (int i=b; i<e; i++){ off[i] = base; base += deg[i]; }
  if (e == N) off[N] = base;                  // duplicate writes benign (same value)
}
__global__ void k_copy(const int* __restrict__ off, int* __restrict__ cur, int N){
  int i = blockIdx.x*256 + threadIdx.x;
  if (i < N) cur[i] = off[i];
}
__global__ void k_self(int* __restrict__ cur, int* __restrict__ srcs, int N){
  int i = blockIdx.x*256 + threadIdx.x;
  if (i < N){ int p = atomicAdd(&cur[i],1); srcs[p] = i; }
}
__global__ void k_scatter(const int* __restrict__ src, const int* __restrict__ dst, int E,
                          int* __restrict__ cur, int* __restrict__ srcs){
  int e = blockIdx.x*256 + threadIdx.x;
  if (e < E){ int p = atomicAdd(&cur[dst[e]],1); srcs[p] = src[e]; }
}

// ---------------- GEMM: out[n, m0..] = A[n,:] @ W[:, col0+m] ----------------
template<int K, int M>
__global__ __launch_bounds__(256) void k_gemm(
    const float* __restrict__ A, const float* __restrict__ W, int ldw, int col0,
    float* __restrict__ out, int N)
{
  constexpr int KT = 64;
  constexpr int TX = M/4;
  __shared__ float As[64][KT+1];
  __shared__ alignas(16) float Ws[KT][M];
  int t = threadIdx.x;
  int base = blockIdx.x*64;
  int tx = t % TX, ty = t / TX;
  bool act = ty < 16;
  int n0 = ty*4, m0 = tx*4;
  float acc[4][4] = {};
  for (int kt=0; kt<K; kt+=KT){
    for (int i=t; i<64*(KT/4); i+=256){
      int n  = i >> 4;        // KT/4 == 16
      int kq = i & 15;
      float4 v = make_float4(0.f,0.f,0.f,0.f);
      int gn = base + n;
      if (gn < N) v = *(const float4*)(A + (size_t)gn*K + kt + kq*4);
      As[n][kq*4+0]=v.x; As[n][kq*4+1]=v.y; As[n][kq*4+2]=v.z; As[n][kq*4+3]=v.w;
    }
    for (int i=t; i<KT*(M/4); i+=256){
      int k = i/(M/4), mq = i%(M/4);
      *(float4*)&Ws[k][mq*4] = *(const float4*)(W + (size_t)(kt+k)*ldw + col0 + mq*4);
    }
    __syncthreads();
    if (act){
      #pragma unroll 8
      for (int k=0;k<KT;k++){
        float4 w = *(const float4*)&Ws[k][m0];
        float av0 = As[n0+0][k], av1 = As[n0+1][k], av2 = As[n0+2][k], av3 = As[n0+3][k];
        acc[0][0]=fmaf(av0,w.x,acc[0][0]); acc[0][1]=fmaf(av0,w.y,acc[0][1]);
        acc[0][2]=fmaf(av0,w.z,acc[0][2]); acc[0][3]=fmaf(av0,w.w,acc[0][3]);
        acc[1][0]=fmaf(av1,w.x,acc[1][0]); acc[1][1]=fmaf(av1,w.y,acc[1][1]);
        acc[1][2]=fmaf(av1,w.z,acc[1][2]); acc[1][3]=fmaf(av1,w.w,acc[1][3]);
        acc[2][0]=fmaf(av2,w.x,acc[2][0]); acc[2][1]=fmaf(av2,w.y,acc[2][1]);
        acc[2][2]=fmaf(av2,w.z,acc[2][2]); acc[2][3]=fmaf(av2,w.w,acc[2][3]);
        acc[3][0]=fmaf(av3,w.x,acc[3][0]); acc[3][1]=fmaf(av3,w.y,acc[3][1]);
        acc[3][2]=fmaf(av3,w.z,acc[3][2]); acc[3][3]=fmaf(av3,w.w,acc[3][3]);
      }
    }
    __syncthreads();
  }
  if (act){
    #pragma unroll
    for (int i=0;i<4;i++){
      int gn = base + n0 + i;
      if (gn < N){
        float4 v = make_float4(acc[i][0],acc[i][1],acc[i][2],acc[i][3]);
        *(float4*)(out + (size_t)gn*M + m0) = v;
      }
    }
  }
}

// ---------------- attention logits (layers 1-4, H=8, C=8) ----------------
__global__ void k_al(const float* __restrict__ h, const float* __restrict__ a_s,
                     const float* __restrict__ a_d, float* __restrict__ al_s,
                     float* __restrict__ al_d, int total /* N*8 */)
{
  int idx = blockIdx.x*256 + threadIdx.x;
  if (idx >= total) return;
  int hd = idx & 7;
  const float4* hp = (const float4*)(h + (size_t)idx*8);   // h[n*64 + hd*8] == h[idx*8]
  float4 h0 = hp[0], h1 = hp[1];
  const float4* sp = (const float4*)(a_s + hd*8);
  const float4* dp = (const float4*)(a_d + hd*8);
  float4 s0 = sp[0], s1 = sp[1], d0 = dp[0], d1 = dp[1];
  al_s[idx] = h0.x*s0.x + h0.y*s0.y + h0.z*s0.z + h0.w*s0.w
            + h1.x*s1.x + h1.y*s1.y + h1.z*s1.z + h1.w*s1.w;
  al_d[idx] = h0.x*d0.x + h0.y*d0.y + h0.z*d0.z + h0.w*d0.w
            + h1.x*d1.x + h1.y*d1.y + h1.z*d1.z + h1.w*d1.w;
}

// layer 5 per-head (C=40)
__global__ void k_al5(const float* __restrict__ h5, const float* __restrict__ asr,
                      const float* __restrict__ adr, float* __restrict__ al_s,
                      float* __restrict__ al_d, int N)
{
  int n = blockIdx.x*256 + threadIdx.x;
  if (n >= N) return;
  const float4* hp = (const float4*)(h5 + (size_t)n*40);
  float ds = 0.f, dd = 0.f;
  #pragma unroll
  for (int q=0;q<10;q++){
    float4 v = hp[q];
    float4 a = ((const float4*)asr)[q];
    float4 b = ((const float4*)adr)[q];
    ds += v.x*a.x + v.y*a.y + v.z*a.z + v.w*a.w;
    dd += v.x*b.x + v.y*b.y + v.z*b.z + v.w*b.w;
  }
  al_s[n] = ds; al_d[n] = dd;
}

// ---------------- aggregation (layers 1-4): softmax + gather, M=64 ----------------
__global__ __launch_bounds__(256) void k_agg64(
    const float* __restrict__ h, const float* __restrict__ al_s,
    const float* __restrict__ al_d, const int* __restrict__ off,
    const int* __restrict__ srcs, const float* __restrict__ bias,
    float* __restrict__ outf, int N, int apply_act)
{
  int t = threadIdx.x;
  int node = blockIdx.x*4 + (t >> 6);
  if (node >= N) return;
  int tl = t & 63;
  int hd = tl >> 3;
  int beg = off[node], end = off[node+1];
  float ald = al_d[(size_t)node*8 + hd];
  // pass 1: online max/sum (redundant across the 8 lanes of each head)
  float m = -1e30f, s = 0.f;
  for (int j=beg; j<end; j++){
    int si = srcs[j];
    float e = leaky(al_s[(size_t)si*8 + hd] + ald);
    float mn = fmaxf(m, e);
    s = s*__expf(m - mn) + __expf(e - mn);
    m = mn;
  }
  float inv = 1.f/(s + 1e-16f);
  // pass 2: weighted gather
  float acc = 0.f;
  for (int j=beg; j<end; j++){
    int si = srcs[j];
    float e = leaky(al_s[(size_t)si*8 + hd] + ald);
    float alpha = __expf(e - m)*inv;
    acc = fmaf(alpha, h[(size_t)si*64 + tl], acc);
  }
  float v = acc + bias[tl];
  if (apply_act) v = leaky(v);
  outf[(size_t)node*64 + tl] = v;
}

// layer 5 per-head aggregation (C=40), accumulating across heads
__global__ __launch_bounds__(256) void k_agg40(
    const float* __restrict__ h5, const float* __restrict__ al_s,
    const float* __restrict__ al_d, const int* __restrict__ off,
    const int* __restrict__ srcs, float* __restrict__ acc_out, int N, int first)
{
  int t = threadIdx.x;
  int node = blockIdx.x*4 + (t >> 6);
  if (node >= N) return;
  int tl = t & 63;
  int beg = off[node], end = off[node+1];
  float ald = al_d[node];
  float m = -1e30f, s = 0.f;
  for (int j=beg; j<end; j++){
    int si = srcs[j];
    float e = leaky(al_s[si] + ald);
    float mn = fmaxf(m, e);
    s = s*__expf(m - mn) + __expf(e - mn);
    m = mn;
  }
  float inv = 1.f/(s + 1e-16f);
  if (tl < 40){
    float acc = 0.f;
    for (int j=beg; j<end; j++){
      int si = srcs[j];
      float e = leaky(al_s[si] + ald);
      float alpha = __expf(e - m)*inv;
      acc = fmaf(alpha, h5[(size_t)si*40 + tl], acc);
    }
    size_t o = (size_t)node*40 + tl;
    acc_out[o] = (first ? 0.f : acc_out[o]) + acc;
  }
}

// ---------------- final: mean over heads + bias + log_softmax ----------------
__global__ __launch_bounds__(256) void k_final(
    const float* __restrict__ acc, const float* __restrict__ b5,
    float* __restrict__ out, int N)
{
  int t = threadIdx.x;
  int node = blockIdx.x*4 + (t >> 6);
  if (node >= N) return;
  int tl = t & 63;
  float v = (tl < 40) ? acc[(size_t)node*40 + tl]*0.125f + b5[tl] : -1e30f;
  float m = v;
  #pragma unroll
  for (int o=32;o;o>>=1) m = fmaxf(m, __shfl_xor(m, o, 64));
  float ex = (tl < 40) ? __expf(v - m) : 0.f;
  float s = ex;
  #pragma unroll
  for (int o=32;o;o>>=1) s += __shfl_xor(s, o, 64);
  if (tl < 40) out[(size_t)node*40 + tl] = (v - m) - __logf(s);
}

extern "C" void kernel_launch(void* const* d_in, const int* in_sizes, int n_in,
                              void* d_out, int out_size, void* d_ws, size_t ws_size,
                              hipStream_t stream) {
  const float* x  = (const float*)d_in[0];
  const int*   ei = (const int*)d_in[1];
  const int N = in_sizes[0] / 128;
  const int E = in_sizes[1] / 2;
  const int* esrc = ei;
  const int* edst = ei + E;
  const float* W1 = (const float*)d_in[2];
  const float* as1= (const float*)d_in[3];
  const float* ad1= (const float*)d_in[4];
  const float* b1 = (const float*)d_in[5];
  const float* W2 = (const float*)d_in[6];
  const float* as2= (const float*)d_in[7];
  const float* ad2= (const float*)d_in[8];
  const float* b2 = (const float*)d_in[9];
  const float* W3 = (const float*)d_in[10];
  const float* as3= (const float*)d_in[11];
  const float* ad3= (const float*)d_in[12];
  const float* b3 = (const float*)d_in[13];
  const float* W4 = (const float*)d_in[14];
  const float* as4= (const float*)d_in[15];
  const float* ad4= (const float*)d_in[16];
  const float* b4 = (const float*)d_in[17];
  const float* W5 = (const float*)d_in[18];
  const float* as5= (const float*)d_in[19];
  const float* ad5= (const float*)d_in[20];
  const float* b5 = (const float*)d_in[21];

  char* p = (char*)d_ws;
  auto alloc = [&](size_t bytes)->void*{
    uintptr_t u = (uintptr_t)p;
    u = (u + 255) & ~(uintptr_t)255;
    void* r = (void*)u;
    p = (char*)u + bytes;
    return r;
  };
  int* deg    = (int*)alloc((size_t)N*4);
  int* off    = (int*)alloc((size_t)(N+1)*4);
  int* cur    = (int*)alloc((size_t)N*4);
  int* srcs   = (int*)alloc((size_t)(E+N)*4);
  float* al_s = (float*)alloc((size_t)N*8*4);
  float* al_d = (float*)alloc((size_t)N*8*4);
  float* featA= (float*)alloc((size_t)N*64*4);
  float* featB= (float*)alloc((size_t)N*64*4);
  float* hbuf = (float*)alloc((size_t)N*64*4);

  int gN = (N+255)/256, gE = (E+255)/256, gT = (N+63)/64, gA = N/4;

  // CSR (rebuilt each call; edge_index is constant so result is stable)
  k_init_deg<<<gN,256,0,stream>>>(deg, N);
  k_count  <<<gE,256,0,stream>>>(edst, E, deg);
  k_scan   <<<1,1024,0,stream>>>(deg, off, N);
  k_copy   <<<gN,256,0,stream>>>(off, cur, N);
  k_self   <<<gN,256,0,stream>>>(cur, srcs, N);
  k_scatter<<<gE,256,0,stream>>>(esrc, edst, E, cur, srcs);

  // Layer 1: x[N,128] -> featA
  k_gemm<128,64><<<gT,256,0,stream>>>(x, W1, 64, 0, hbuf, N);
  k_al<<<(N*8+255)/256,256,0,stream>>>(hbuf, as1, ad1, al_s, al_d, N*8);
  k_agg64<<<gA,256,0,stream>>>(hbuf, al_s, al_d, off, srcs, b1, featA, N, 1);

  // Layer 2: featA -> featB
  k_gemm<64,64><<<gT,256,0,stream>>>(featA, W2, 64, 0, hbuf, N);
  k_al<<<(N*8+255)/256,256,0,stream>>>(hbuf, as2, ad2, al_s, al_d, N*8);
  k_agg64<<<gA,256,0,stream>>>(hbuf, al_s, al_d, off, srcs, b2, featB, N, 1);

  // Layer 3: featB -> featA
  k_gemm<64,64><<<gT,256,0,stream>>>(featB, W3, 64, 0, hbuf, N);
  k_al<<<(N*8+255)/256,256,0,stream>>>(hbuf, as3, ad3, al_s, al_d, N*8);
  k_agg64<<<gA,256,0,stream>>>(hbuf, al_s, al_d, off, srcs, b3, featA, N, 1);

  // Layer 4: featA -> featB
  k_gemm<64,64><<<gT,256,0,stream>>>(featA, W4, 64, 0, hbuf, N);
  k_al<<<(N*8+255)/256,256,0,stream>>>(hbuf, as4, ad4, al_s, al_d, N*8);
  k_agg64<<<gA,256,0,stream>>>(hbuf, al_s, al_d, off, srcs, b4, featB, N, 1);

  // Layer 5: featB -> featA (head accumulator, N x 40)
  for (int hd = 0; hd < 8; hd++){
    k_gemm<64,40><<<gT,256,0,stream>>>(featB, W5, 320, hd*40, hbuf, N);
    k_al5<<<gN,256,0,stream>>>(hbuf, as5 + hd*40, ad5 + hd*40, al_s, al_d, N);
    k_agg40<<<gA,256,0,stream>>>(hbuf, al_s, al_d, off, srcs, featA, N, hd==0 ? 1 : 0);
  }

  // mean + bias + log_softmax
  k_final<<<gA,256,0,stream>>>(featA, b5, (float*)d_out, N);
}

// Round 2
// 1664.952 us; speedup vs baseline: 2.5728x; 2.5728x over previous
//
#include <hip/hip_runtime.h>
#include <cstddef>
#include <cstdint>

static __device__ __forceinline__ float leaky(float x){ return x >= 0.f ? x : 0.2f*x; }

// ---------------- CSR build ----------------
__global__ void k_init_deg(int* __restrict__ deg, int N){
  int i = blockIdx.x*256 + threadIdx.x;
  if (i < N) deg[i] = 1;                      // self-loop
}
__global__ void k_count(const int* __restrict__ dst, int E, int* __restrict__ deg){
  int e = blockIdx.x*256 + threadIdx.x;
  if (e < E) atomicAdd(&deg[dst[e]], 1);
}
__global__ __launch_bounds__(1024) void k_scan(const int* __restrict__ deg, int* __restrict__ off, int N){
  __shared__ int part[1024];
  int t = threadIdx.x;
  int chunk = (N + 1023) >> 10;
  int b = t*chunk;
  int e = b + chunk; if (e > N) e = N;
  int s = 0;
  for (int i=b; i<e; i++) s += deg[i];
  part[t] = s;
  __syncthreads();
  for (int o=1; o<1024; o<<=1){
    int v = (t >= o) ? part[t-o] : 0;
    __syncthreads();
    part[t] += v;
    __syncthreads();
  }
  int base = (t==0) ? 0 : part[t-1];
  for (int i=b; i<e; i++){ off[i] = base; base += deg[i]; }
  if (e == N) off[N] = base;
}
__global__ void k_copy(const int* __restrict__ off, int* __restrict__ cur, int N){
  int i = blockIdx.x*256 + threadIdx.x;
  if (i < N) cur[i] = off[i];
}
__global__ void k_self(int* __restrict__ cur, int* __restrict__ srcs, int N){
  int i = blockIdx.x*256 + threadIdx.x;
  if (i < N){ int p = atomicAdd(&cur[i],1); srcs[p] = i; }
}
__global__ void k_scatter(const int* __restrict__ src, const int* __restrict__ dst, int E,
                          int* __restrict__ cur, int* __restrict__ srcs){
  int e = blockIdx.x*256 + threadIdx.x;
  if (e < E){ int p = atomicAdd(&cur[dst[e]],1); srcs[p] = src[e]; }
}

// ---------------- GEMM: out[n, m0..] = A[n,:] @ W[:, col0+m] ----------------
template<int K, int M>
__global__ __launch_bounds__(256) void k_gemm(
    const float* __restrict__ A, const float* __restrict__ W, int ldw, int col0,
    float* __restrict__ out, int N)
{
  constexpr int KT = 64;
  constexpr int TX = M/4;
  __shared__ float As[64][KT+1];
  __shared__ alignas(16) float Ws[KT][M];
  int t = threadIdx.x;
  int base = blockIdx.x*64;
  int tx = t % TX, ty = t / TX;
  bool act = ty < 16;
  int n0 = ty*4, m0 = tx*4;
  float acc[4][4] = {};
  for (int kt=0; kt<K; kt+=KT){
    for (int i=t; i<64*(KT/4); i+=256){
      int n  = i >> 4;
      int kq = i & 15;
      float4 v = make_float4(0.f,0.f,0.f,0.f);
      int gn = base + n;
      if (gn < N) v = *(const float4*)(A + (size_t)gn*K + kt + kq*4);
      As[n][kq*4+0]=v.x; As[n][kq*4+1]=v.y; As[n][kq*4+2]=v.z; As[n][kq*4+3]=v.w;
    }
    for (int i=t; i<KT*(M/4); i+=256){
      int k = i/(M/4), mq = i%(M/4);
      *(float4*)&Ws[k][mq*4] = *(const float4*)(W + (size_t)(kt+k)*ldw + col0 + mq*4);
    }
    __syncthreads();
    if (act){
      #pragma unroll 8
      for (int k=0;k<KT;k++){
        float4 w = *(const float4*)&Ws[k][m0];
        float av0 = As[n0+0][k], av1 = As[n0+1][k], av2 = As[n0+2][k], av3 = As[n0+3][k];
        acc[0][0]=fmaf(av0,w.x,acc[0][0]); acc[0][1]=fmaf(av0,w.y,acc[0][1]);
        acc[0][2]=fmaf(av0,w.z,acc[0][2]); acc[0][3]=fmaf(av0,w.w,acc[0][3]);
        acc[1][0]=fmaf(av1,w.x,acc[1][0]); acc[1][1]=fmaf(av1,w.y,acc[1][1]);
        acc[1][2]=fmaf(av1,w.z,acc[1][2]); acc[1][3]=fmaf(av1,w.w,acc[1][3]);
        acc[2][0]=fmaf(av2,w.x,acc[2][0]); acc[2][1]=fmaf(av2,w.y,acc[2][1]);
        acc[2][2]=fmaf(av2,w.z,acc[2][2]); acc[2][3]=fmaf(av2,w.w,acc[2][3]);
        acc[3][0]=fmaf(av3,w.x,acc[3][0]); acc[3][1]=fmaf(av3,w.y,acc[3][1]);
        acc[3][2]=fmaf(av3,w.z,acc[3][2]); acc[3][3]=fmaf(av3,w.w,acc[3][3]);
      }
    }
    __syncthreads();
  }
  if (act){
    #pragma unroll
    for (int i=0;i<4;i++){
      int gn = base + n0 + i;
      if (gn < N){
        float4 v = make_float4(acc[i][0],acc[i][1],acc[i][2],acc[i][3]);
        *(float4*)(out + (size_t)gn*M + m0) = v;
      }
    }
  }
}

// ---------------- attention logits (layers 1-4, H=8, C=8) ----------------
__global__ void k_al(const float* __restrict__ h, const float* __restrict__ a_s,
                     const float* __restrict__ a_d, float* __restrict__ al_s,
                     float* __restrict__ al_d, int total /* N*8 */)
{
  int idx = blockIdx.x*256 + threadIdx.x;
  if (idx >= total) return;
  int hd = idx & 7;
  const float4* hp = (const float4*)(h + (size_t)idx*8);
  float4 h0 = hp[0], h1 = hp[1];
  const float4* sp = (const float4*)(a_s + hd*8);
  const float4* dp = (const float4*)(a_d + hd*8);
  float4 s0 = sp[0], s1 = sp[1], d0 = dp[0], d1 = dp[1];
  al_s[idx] = h0.x*s0.x + h0.y*s0.y + h0.z*s0.z + h0.w*s0.w
            + h1.x*s1.x + h1.y*s1.y + h1.z*s1.z + h1.w*s1.w;
  al_d[idx] = h0.x*d0.x + h0.y*d0.y + h0.z*d0.z + h0.w*d0.w
            + h1.x*d1.x + h1.y*d1.y + h1.z*d1.z + h1.w*d1.w;
}

// ---------------- aggregation (layers 1-4): softmax + gather, M=64 ----------------
__global__ __launch_bounds__(256) void k_agg64(
    const float* __restrict__ h, const float* __restrict__ al_s,
    const float* __restrict__ al_d, const int* __restrict__ off,
    const int* __restrict__ srcs, const float* __restrict__ bias,
    float* __restrict__ outf, int N, int apply_act)
{
  int t = threadIdx.x;
  int node = blockIdx.x*4 + (t >> 6);
  if (node >= N) return;
  int tl = t & 63;
  int hd = tl >> 3;
  int sub = tl & 7;
  int beg = off[node], end = off[node+1];
  float ald = al_d[(size_t)node*8 + hd];
  // pass 1: cooperative online max/sum — 8 lanes per head, strided edges
  float m = -1e30f, s = 0.f;
  for (int j=beg+sub; j<end; j+=8){
    int si = srcs[j];
    float e = leaky(al_s[(size_t)si*8 + hd] + ald);
    float mn = fmaxf(m, e);
    s = s*__expf(m - mn) + __expf(e - mn);
    m = mn;
  }
  #pragma unroll
  for (int o=1;o<8;o<<=1){
    float mo = __shfl_xor(m, o, 64);
    float so = __shfl_xor(s, o, 64);
    float mn = fmaxf(m, mo);
    s = s*__expf(m - mn) + so*__expf(mo - mn);
    m = mn;
  }
  float inv = 1.f/(s + 1e-16f);
  // pass 2: weighted gather, unroll x2, inv hoisted
  float acc0 = 0.f, acc1 = 0.f;
  int j = beg;
  for (; j+1 < end; j += 2){
    int s0 = srcs[j], s1 = srcs[j+1];
    float e0 = leaky(al_s[(size_t)s0*8 + hd] + ald);
    float e1 = leaky(al_s[(size_t)s1*8 + hd] + ald);
    float a0 = __expf(e0 - m);
    float a1 = __expf(e1 - m);
    acc0 = fmaf(a0, h[(size_t)s0*64 + tl], acc0);
    acc1 = fmaf(a1, h[(size_t)s1*64 + tl], acc1);
  }
  if (j < end){
    int s0 = srcs[j];
    float e0 = leaky(al_s[(size_t)s0*8 + hd] + ald);
    acc0 = fmaf(__expf(e0 - m), h[(size_t)s0*64 + tl], acc0);
  }
  float v = (acc0 + acc1)*inv + bias[tl];
  if (apply_act) v = leaky(v);
  outf[(size_t)node*64 + tl] = v;
}

// ---------------- layer 5: folded attention vectors ----------------
// ws[h][k] = sum_c W5[k, h*40+c] * a_s5[h,c]  (and wd with a_d5)
__global__ __launch_bounds__(512) void k_ws(const float* __restrict__ W5,
                                            const float* __restrict__ as5,
                                            const float* __restrict__ ad5,
                                            float* __restrict__ ws, float* __restrict__ wd){
  int t = threadIdx.x;            // 0..511
  int h = t >> 6, k = t & 63;
  float s = 0.f, d = 0.f;
  #pragma unroll 8
  for (int c=0;c<40;c++){
    float w = W5[(size_t)k*320 + h*40 + c];
    s = fmaf(w, as5[h*40+c], s);
    d = fmaf(w, ad5[h*40+c], d);
  }
  ws[h*64+k] = s; wd[h*64+k] = d;
}

// al_s[n,h] = featB[n,:] . ws[h,:]
__global__ void k_al5b(const float* __restrict__ feat, const float* __restrict__ ws,
                       const float* __restrict__ wd, float* __restrict__ al_s,
                       float* __restrict__ al_d, int total /* N*8 */)
{
  int idx = blockIdx.x*256 + threadIdx.x;
  if (idx >= total) return;
  int n = idx >> 3, h = idx & 7;
  const float4* fp = (const float4*)(feat + (size_t)n*64);
  const float4* ap = (const float4*)(ws + h*64);
  const float4* bp = (const float4*)(wd + h*64);
  float s = 0.f, d = 0.f;
  #pragma unroll
  for (int q=0;q<16;q++){
    float4 f = fp[q], a = ap[q], b = bp[q];
    s += f.x*a.x + f.y*a.y + f.z*a.z + f.w*a.w;
    d += f.x*b.x + f.y*b.y + f.z*b.z + f.w*b.w;
  }
  al_s[idx] = s; al_d[idx] = d;
}

// per node: softmax stats (all 8 heads), input-space aggregation (8x64 per node),
// then fused out = mean_h(agg_h @ W5_h) + b5, log_softmax. One wave per node.
__global__ __launch_bounds__(256) void k_agg5(
    const float* __restrict__ feat, const float* __restrict__ al_s,
    const float* __restrict__ al_d, const int* __restrict__ off,
    const int* __restrict__ srcs, const float* __restrict__ W5,
    const float* __restrict__ b5, float* __restrict__ out, int N)
{
  __shared__ float agg[4][8][64];
  int t = threadIdx.x;
  int w = t >> 6;
  int node = blockIdx.x*4 + w;
  int tl = t & 63;
  int hd = tl >> 3;
  int sub = tl & 7;
  bool valid = node < N;
  int beg = 0, end = 0;
  float ald = 0.f;
  if (valid){ beg = off[node]; end = off[node+1]; ald = al_d[(size_t)node*8 + hd]; }
  // pass 1: cooperative stats
  float m = -1e30f, s = 0.f;
  for (int j=beg+sub; j<end; j+=8){
    int si = srcs[j];
    float e = leaky(al_s[(size_t)si*8 + hd] + ald);
    float mn = fmaxf(m, e);
    s = s*__expf(m - mn) + __expf(e - mn);
    m = mn;
  }
  #pragma unroll
  for (int o=1;o<8;o<<=1){
    float mo = __shfl_xor(m, o, 64);
    float so = __shfl_xor(s, o, 64);
    float mn = fmaxf(m, mo);
    s = s*__expf(m - mn) + so*__expf(mo - mn);
    m = mn;
  }
  float inv = 1.f/(s + 1e-16f);
  // pass 2: gather feat rows once per edge; 8 head-accumulators per lane
  float acch[8] = {0.f,0.f,0.f,0.f,0.f,0.f,0.f,0.f};
  #pragma unroll 2
  for (int j=beg; j<end; ++j){
    int si = srcs[j];
    float e = leaky(al_s[(size_t)si*8 + hd] + ald);
    float a = __expf(e - m)*inv;               // alpha for head hd (uniform in group)
    float hv = feat[(size_t)si*64 + tl];
    #pragma unroll
    for (int h2=0; h2<8; h2++){
      float ah = __shfl(a, h2*8 + sub, 64);
      acch[h2] = fmaf(ah, hv, acch[h2]);
    }
  }
  #pragma unroll
  for (int h2=0; h2<8; h2++) agg[w][h2][tl] = acch[h2];
  __syncthreads();
  if (!valid) return;
  // fused final GEMM: out[c] = (1/8) sum_h sum_k agg[h][k]*W5[k, h*40+c] + b5[c]
  float o = 0.f;
  if (tl < 40){
    #pragma unroll
    for (int h2=0; h2<8; h2++){
      const float* Wl = W5 + h2*40 + tl;
      const float* ag = &agg[w][h2][0];
      #pragma unroll 8
      for (int k=0;k<64;k++) o = fmaf(ag[k], Wl[(size_t)k*320], o);
    }
    o = o*0.125f + b5[tl];
  }
  float v = (tl < 40) ? o : -1e30f;
  float mx = v;
  #pragma unroll
  for (int of=32; of; of>>=1) mx = fmaxf(mx, __shfl_xor(mx, of, 64));
  float ex = (tl < 40) ? __expf(v - mx) : 0.f;
  float se = ex;
  #pragma unroll
  for (int of=32; of; of>>=1) se += __shfl_xor(se, of, 64);
  if (tl < 40) out[(size_t)node*40 + tl] = (v - mx) - __logf(se);
}

extern "C" void kernel_launch(void* const* d_in, const int* in_sizes, int n_in,
                              void* d_out, int out_size, void* d_ws, size_t ws_size,
                              hipStream_t stream) {
  const float* x  = (const float*)d_in[0];
  const int*   ei = (const int*)d_in[1];
  const int N = in_sizes[0] / 128;
  const int E = in_sizes[1] / 2;
  const int* esrc = ei;
  const int* edst = ei + E;
  const float* W1 = (const float*)d_in[2];
  const float* as1= (const float*)d_in[3];
  const float* ad1= (const float*)d_in[4];
  const float* b1 = (const float*)d_in[5];
  const float* W2 = (const float*)d_in[6];
  const float* as2= (const float*)d_in[7];
  const float* ad2= (const float*)d_in[8];
  const float* b2 = (const float*)d_in[9];
  const float* W3 = (const float*)d_in[10];
  const float* as3= (const float*)d_in[11];
  const float* ad3= (const float*)d_in[12];
  const float* b3 = (const float*)d_in[13];
  const float* W4 = (const float*)d_in[14];
  const float* as4= (const float*)d_in[15];
  const float* ad4= (const float*)d_in[16];
  const float* b4 = (const float*)d_in[17];
  const float* W5 = (const float*)d_in[18];
  const float* as5= (const float*)d_in[19];
  const float* ad5= (const float*)d_in[20];
  const float* b5 = (const float*)d_in[21];

  char* p = (char*)d_ws;
  auto alloc = [&](size_t bytes)->void*{
    uintptr_t u = (uintptr_t)p;
    u = (u + 255) & ~(uintptr_t)255;
    void* r = (void*)u;
    p = (char*)u + bytes;
    return r;
  };
  int* deg    = (int*)alloc((size_t)N*4);
  int* off    = (int*)alloc((size_t)(N+1)*4);
  int* cur    = (int*)alloc((size_t)N*4);
  int* srcs   = (int*)alloc((size_t)(E+N)*4);
  float* al_s = (float*)alloc((size_t)N*8*4);
  float* al_d = (float*)alloc((size_t)N*8*4);
  float* featA= (float*)alloc((size_t)N*64*4);
  float* featB= (float*)alloc((size_t)N*64*4);
  float* hbuf = (float*)alloc((size_t)N*64*4);
  float* wsb  = (float*)alloc((size_t)8*64*4);
  float* wdb  = (float*)alloc((size_t)8*64*4);

  int gN = (N+255)/256, gE = (E+255)/256, gT = (N+63)/64, gA = (N+3)/4;

  // CSR
  k_init_deg<<<gN,256,0,stream>>>(deg, N);
  k_count  <<<gE,256,0,stream>>>(edst, E, deg);
  k_scan   <<<1,1024,0,stream>>>(deg, off, N);
  k_copy   <<<gN,256,0,stream>>>(off, cur, N);
  k_self   <<<gN,256,0,stream>>>(cur, srcs, N);
  k_scatter<<<gE,256,0,stream>>>(esrc, edst, E, cur, srcs);

  // Layer 1
  k_gemm<128,64><<<gT,256,0,stream>>>(x, W1, 64, 0, hbuf, N);
  k_al<<<(N*8+255)/256,256,0,stream>>>(hbuf, as1, ad1, al_s, al_d, N*8);
  k_agg64<<<gA,256,0,stream>>>(hbuf, al_s, al_d, off, srcs, b1, featA, N, 1);

  // Layer 2
  k_gemm<64,64><<<gT,256,0,stream>>>(featA, W2, 64, 0, hbuf, N);
  k_al<<<(N*8+255)/256,256,0,stream>>>(hbuf, as2, ad2, al_s, al_d, N*8);
  k_agg64<<<gA,256,0,stream>>>(hbuf, al_s, al_d, off, srcs, b2, featB, N, 1);

  // Layer 3
  k_gemm<64,64><<<gT,256,0,stream>>>(featB, W3, 64, 0, hbuf, N);
  k_al<<<(N*8+255)/256,256,0,stream>>>(hbuf, as3, ad3, al_s, al_d, N*8);
  k_agg64<<<gA,256,0,stream>>>(hbuf, al_s, al_d, off, srcs, b3, featA, N, 1);

  // Layer 4
  k_gemm<64,64><<<gT,256,0,stream>>>(featA, W4, 64, 0, hbuf, N);
  k_al<<<(N*8+255)/256,256,0,stream>>>(hbuf, as4, ad4, al_s, al_d, N*8);
  k_agg64<<<gA,256,0,stream>>>(hbuf, al_s, al_d, off, srcs, b4, featB, N, 1);

  // Layer 5: folded attention + input-space aggregation + fused output
  k_ws  <<<1,512,0,stream>>>(W5, as5, ad5, wsb, wdb);
  k_al5b<<<(N*8+255)/256,256,0,stream>>>(featB, wsb, wdb, al_s, al_d, N*8);
  k_agg5<<<gA,256,0,stream>>>(featB, al_s, al_d, off, srcs, W5, b5, (float*)d_out, N);
}

// Round 3
// 1270.634 us; speedup vs baseline: 3.3712x; 1.3103x over previous
//
#include <hip/hip_runtime.h>
#include <cstddef>
#include <cstdint>

static __device__ __forceinline__ float leaky(float x){ return x >= 0.f ? x : 0.2f*x; }

// ---------------- CSR build ----------------
__global__ void k_init_deg(int* __restrict__ deg, int N){
  int i = blockIdx.x*256 + threadIdx.x;
  if (i < N) deg[i] = 1;                      // self-loop
}
__global__ void k_count(const int* __restrict__ dst, int E, int* __restrict__ deg){
  int e = blockIdx.x*256 + threadIdx.x;
  if (e < E) atomicAdd(&deg[dst[e]], 1);
}
__global__ __launch_bounds__(1024) void k_scan(const int* __restrict__ deg, int* __restrict__ off, int N){
  __shared__ int part[1024];
  int t = threadIdx.x;
  int chunk = (N + 1023) >> 10;
  int b = t*chunk;
  int e = b + chunk; if (e > N) e = N;
  int s = 0;
  for (int i=b; i<e; i++) s += deg[i];
  part[t] = s;
  __syncthreads();
  for (int o=1; o<1024; o<<=1){
    int v = (t >= o) ? part[t-o] : 0;
    __syncthreads();
    part[t] += v;
    __syncthreads();
  }
  int base = (t==0) ? 0 : part[t-1];
  for (int i=b; i<e; i++){ off[i] = base; base += deg[i]; }
  if (e == N) off[N] = base;
}
__global__ void k_copy(const int* __restrict__ off, int* __restrict__ cur, int N){
  int i = blockIdx.x*256 + threadIdx.x;
  if (i < N) cur[i] = off[i];
}
__global__ void k_self(int* __restrict__ cur, int* __restrict__ srcs, int N){
  int i = blockIdx.x*256 + threadIdx.x;
  if (i < N){ int p = atomicAdd(&cur[i],1); srcs[p] = i; }
}
__global__ void k_scatter(const int* __restrict__ src, const int* __restrict__ dst, int E,
                          int* __restrict__ cur, int* __restrict__ srcs){
  int e = blockIdx.x*256 + threadIdx.x;
  if (e < E){ int p = atomicAdd(&cur[dst[e]],1); srcs[p] = src[e]; }
}

// ---------------- GEMM: out[n, m] = A[n,:] @ W[:, m] ----------------
template<int K, int M>
__global__ __launch_bounds__(256) void k_gemm(
    const float* __restrict__ A, const float* __restrict__ W, int ldw, int col0,
    float* __restrict__ out, int N)
{
  constexpr int KT = 64;
  constexpr int TX = M/4;
  __shared__ float As[64][KT+1];
  __shared__ alignas(16) float Ws[KT][M];
  int t = threadIdx.x;
  int base = blockIdx.x*64;
  int tx = t % TX, ty = t / TX;
  bool act = ty < 16;
  int n0 = ty*4, m0 = tx*4;
  float acc[4][4] = {};
  for (int kt=0; kt<K; kt+=KT){
    for (int i=t; i<64*(KT/4); i+=256){
      int n  = i >> 4;
      int kq = i & 15;
      float4 v = make_float4(0.f,0.f,0.f,0.f);
      int gn = base + n;
      if (gn < N) v = *(const float4*)(A + (size_t)gn*K + kt + kq*4);
      As[n][kq*4+0]=v.x; As[n][kq*4+1]=v.y; As[n][kq*4+2]=v.z; As[n][kq*4+3]=v.w;
    }
    for (int i=t; i<KT*(M/4); i+=256){
      int k = i/(M/4), mq = i%(M/4);
      *(float4*)&Ws[k][mq*4] = *(const float4*)(W + (size_t)(kt+k)*ldw + col0 + mq*4);
    }
    __syncthreads();
    if (act){
      #pragma unroll 8
      for (int k=0;k<KT;k++){
        float4 w = *(const float4*)&Ws[k][m0];
        float av0 = As[n0+0][k], av1 = As[n0+1][k], av2 = As[n0+2][k], av3 = As[n0+3][k];
        acc[0][0]=fmaf(av0,w.x,acc[0][0]); acc[0][1]=fmaf(av0,w.y,acc[0][1]);
        acc[0][2]=fmaf(av0,w.z,acc[0][2]); acc[0][3]=fmaf(av0,w.w,acc[0][3]);
        acc[1][0]=fmaf(av1,w.x,acc[1][0]); acc[1][1]=fmaf(av1,w.y,acc[1][1]);
        acc[1][2]=fmaf(av1,w.z,acc[1][2]); acc[1][3]=fmaf(av1,w.w,acc[1][3]);
        acc[2][0]=fmaf(av2,w.x,acc[2][0]); acc[2][1]=fmaf(av2,w.y,acc[2][1]);
        acc[2][2]=fmaf(av2,w.z,acc[2][2]); acc[2][3]=fmaf(av2,w.w,acc[2][3]);
        acc[3][0]=fmaf(av3,w.x,acc[3][0]); acc[3][1]=fmaf(av3,w.y,acc[3][1]);
        acc[3][2]=fmaf(av3,w.z,acc[3][2]); acc[3][3]=fmaf(av3,w.w,acc[3][3]);
      }
    }
    __syncthreads();
  }
  if (act){
    #pragma unroll
    for (int i=0;i<4;i++){
      int gn = base + n0 + i;
      if (gn < N){
        float4 v = make_float4(acc[i][0],acc[i][1],acc[i][2],acc[i][3]);
        *(float4*)(out + (size_t)gn*M + m0) = v;
      }
    }
  }
}

// ---------------- attention logits (layers 1-4, H=8, C=8) ----------------
__global__ void k_al(const float* __restrict__ h, const float* __restrict__ a_s,
                     const float* __restrict__ a_d, float* __restrict__ al_s,
                     float* __restrict__ al_d, int total /* N*8 */)
{
  int idx = blockIdx.x*256 + threadIdx.x;
  if (idx >= total) return;
  int hd = idx & 7;
  const float4* hp = (const float4*)(h + (size_t)idx*8);
  float4 h0 = hp[0], h1 = hp[1];
  const float4* sp = (const float4*)(a_s + hd*8);
  const float4* dp = (const float4*)(a_d + hd*8);
  float4 s0 = sp[0], s1 = sp[1], d0 = dp[0], d1 = dp[1];
  al_s[idx] = h0.x*s0.x + h0.y*s0.y + h0.z*s0.z + h0.w*s0.w
            + h1.x*s1.x + h1.y*s1.y + h1.z*s1.z + h1.w*s1.w;
  al_d[idx] = h0.x*d0.x + h0.y*d0.y + h0.z*d0.z + h0.w*d0.w
            + h1.x*d1.x + h1.y*d1.y + h1.z*d1.z + h1.w*d1.w;
}

// ---------------- aggregation (layers 1-4): single-pass, 8 lanes per node ----------------
// lane = (node grp, sub); sub == head == output col-block [sub*8, sub*8+8)
__global__ __launch_bounds__(256) void k_agg64(
    const float* __restrict__ h, const float* __restrict__ al_s,
    const float* __restrict__ al_d, const int* __restrict__ off,
    const int* __restrict__ srcs, const float* __restrict__ bias,
    float* __restrict__ outf, int N, int apply_act)
{
  int t = threadIdx.x;
  int grp = t >> 3;              // 0..31: node within block
  int sub = t & 7;               // head / col-block
  int node = blockIdx.x*32 + grp;
  if (node >= N) return;
  int beg = off[node], end = off[node+1];
  float ald = al_d[(size_t)node*8 + sub];
  float s = 0.f;
  float acc[8] = {0.f,0.f,0.f,0.f,0.f,0.f,0.f,0.f};
  int j = beg;
  for (; j+1 < end; j += 2){
    int s0 = srcs[j], s1 = srcs[j+1];
    float e0 = leaky(al_s[(size_t)s0*8 + sub] + ald);
    float e1 = leaky(al_s[(size_t)s1*8 + sub] + ald);
    float a0 = __expf(e0), a1 = __expf(e1);
    const float4* f0 = (const float4*)(h + (size_t)s0*64 + sub*8);
    const float4* f1 = (const float4*)(h + (size_t)s1*64 + sub*8);
    float4 u0 = f0[0], u1 = f0[1];
    float4 w0 = f1[0], w1 = f1[1];
    s += a0 + a1;
    acc[0]=fmaf(a0,u0.x,acc[0]); acc[1]=fmaf(a0,u0.y,acc[1]);
    acc[2]=fmaf(a0,u0.z,acc[2]); acc[3]=fmaf(a0,u0.w,acc[3]);
    acc[4]=fmaf(a0,u1.x,acc[4]); acc[5]=fmaf(a0,u1.y,acc[5]);
    acc[6]=fmaf(a0,u1.z,acc[6]); acc[7]=fmaf(a0,u1.w,acc[7]);
    acc[0]=fmaf(a1,w0.x,acc[0]); acc[1]=fmaf(a1,w0.y,acc[1]);
    acc[2]=fmaf(a1,w0.z,acc[2]); acc[3]=fmaf(a1,w0.w,acc[3]);
    acc[4]=fmaf(a1,w1.x,acc[4]); acc[5]=fmaf(a1,w1.y,acc[5]);
    acc[6]=fmaf(a1,w1.z,acc[6]); acc[7]=fmaf(a1,w1.w,acc[7]);
  }
  if (j < end){
    int s0 = srcs[j];
    float e0 = leaky(al_s[(size_t)s0*8 + sub] + ald);
    float a0 = __expf(e0);
    const float4* f0 = (const float4*)(h + (size_t)s0*64 + sub*8);
    float4 u0 = f0[0], u1 = f0[1];
    s += a0;
    acc[0]=fmaf(a0,u0.x,acc[0]); acc[1]=fmaf(a0,u0.y,acc[1]);
    acc[2]=fmaf(a0,u0.z,acc[2]); acc[3]=fmaf(a0,u0.w,acc[3]);
    acc[4]=fmaf(a0,u1.x,acc[4]); acc[5]=fmaf(a0,u1.y,acc[5]);
    acc[6]=fmaf(a0,u1.z,acc[6]); acc[7]=fmaf(a0,u1.w,acc[7]);
  }
  float inv = 1.f/(s + 1e-16f);
  const float4* bp = (const float4*)(bias + sub*8);
  float4 b0 = bp[0], b1 = bp[1];
  float4 o0, o1;
  o0.x = acc[0]*inv + b0.x; o0.y = acc[1]*inv + b0.y;
  o0.z = acc[2]*inv + b0.z; o0.w = acc[3]*inv + b0.w;
  o1.x = acc[4]*inv + b1.x; o1.y = acc[5]*inv + b1.y;
  o1.z = acc[6]*inv + b1.z; o1.w = acc[7]*inv + b1.w;
  if (apply_act){
    o0.x = leaky(o0.x); o0.y = leaky(o0.y); o0.z = leaky(o0.z); o0.w = leaky(o0.w);
    o1.x = leaky(o1.x); o1.y = leaky(o1.y); o1.z = leaky(o1.z); o1.w = leaky(o1.w);
  }
  float* op = outf + (size_t)node*64 + sub*8;
  *(float4*)op = o0; *(float4*)(op+4) = o1;
}

// ---------------- layer 5: folded attention vectors ----------------
__global__ __launch_bounds__(512) void k_ws(const float* __restrict__ W5,
                                            const float* __restrict__ as5,
                                            const float* __restrict__ ad5,
                                            float* __restrict__ ws, float* __restrict__ wd){
  int t = threadIdx.x;            // 0..511
  int h = t >> 6, k = t & 63;
  float s = 0.f, d = 0.f;
  #pragma unroll 8
  for (int c=0;c<40;c++){
    float w = W5[(size_t)k*320 + h*40 + c];
    s = fmaf(w, as5[h*40+c], s);
    d = fmaf(w, ad5[h*40+c], d);
  }
  ws[h*64+k] = s; wd[h*64+k] = d;
}

__global__ void k_al5b(const float* __restrict__ feat, const float* __restrict__ ws,
                       const float* __restrict__ wd, float* __restrict__ al_s,
                       float* __restrict__ al_d, int total /* N*8 */)
{
  int idx = blockIdx.x*256 + threadIdx.x;
  if (idx >= total) return;
  int n = idx >> 3, h = idx & 7;
  const float4* fp = (const float4*)(feat + (size_t)n*64);
  const float4* ap = (const float4*)(ws + h*64);
  const float4* bp = (const float4*)(wd + h*64);
  float s = 0.f, d = 0.f;
  #pragma unroll
  for (int q=0;q<16;q++){
    float4 f = fp[q], a = ap[q], b = bp[q];
    s += f.x*a.x + f.y*a.y + f.z*a.z + f.w*a.w;
    d += f.x*b.x + f.y*b.y + f.z*b.z + f.w*b.w;
  }
  al_s[idx] = s; al_d[idx] = d;
}

// ---------------- layer 5 aggregation in input space -> z[local_n][h*64+k] ----------------
// one wave per node; lane: hd = tl&7 (head), cb = tl>>3 (col-block of 8)
__global__ __launch_bounds__(256) void k_agg5z(
    const float* __restrict__ feat, const float* __restrict__ al_s,
    const float* __restrict__ al_d, const int* __restrict__ off,
    const int* __restrict__ srcs, float* __restrict__ z, int base, int cnt)
{
  int t = threadIdx.x;
  int w = t >> 6;
  int ln = blockIdx.x*4 + w;     // local node
  if (ln >= cnt) return;
  int node = base + ln;
  int tl = t & 63;
  int hd = tl & 7;
  int cb = tl >> 3;
  int beg = off[node], end = off[node+1];
  float ald = al_d[(size_t)node*8 + hd];
  int lanebase = hd*4;           // bpermute byte base: lane (cb=e, hd) = e*8+hd
  int cbo = cb*8;
  float s = 0.f;
  float acc[8] = {0.f,0.f,0.f,0.f,0.f,0.f,0.f,0.f};
  for (int jb = beg; jb < end; jb += 8){
    int j = jb + cb;
    float atil = 0.f; int si = 0;
    if (j < end){
      si = srcs[j];
      atil = __expf(leaky(al_s[(size_t)si*8 + hd] + ald));
    }
    s += atil;
    #pragma unroll 8
    for (int e = 0; e < 8; e++){
      if (jb + e >= end) break;
      float ae = __uint_as_float(__builtin_amdgcn_ds_bpermute(lanebase + e*32, __float_as_uint(atil)));
      int sie = __builtin_amdgcn_readlane(si, e*8);
      const float4* fp = (const float4*)(feat + (size_t)sie*64 + cbo);
      float4 v0 = fp[0], v1 = fp[1];
      acc[0]=fmaf(ae,v0.x,acc[0]); acc[1]=fmaf(ae,v0.y,acc[1]);
      acc[2]=fmaf(ae,v0.z,acc[2]); acc[3]=fmaf(ae,v0.w,acc[3]);
      acc[4]=fmaf(ae,v1.x,acc[4]); acc[5]=fmaf(ae,v1.y,acc[5]);
      acc[6]=fmaf(ae,v1.z,acc[6]); acc[7]=fmaf(ae,v1.w,acc[7]);
    }
  }
  // sum s over cb lanes (xor bits 3,4,5), per head
  s += __shfl_xor(s, 8, 64);
  s += __shfl_xor(s, 16, 64);
  s += __shfl_xor(s, 32, 64);
  float inv = 1.f/(s + 1e-16f);
  float4 o0 = make_float4(acc[0]*inv, acc[1]*inv, acc[2]*inv, acc[3]*inv);
  float4 o1 = make_float4(acc[4]*inv, acc[5]*inv, acc[6]*inv, acc[7]*inv);
  float* zp = z + (size_t)ln*512 + hd*64 + cbo;
  *(float4*)zp = o0; *(float4*)(zp+4) = o1;
}

// ---------------- layer 5 output GEMM: out5[n][c] = sum_{h,k} z[n][h*64+k] W5[k][h*40+c] ----------------
__global__ __launch_bounds__(256) void k_gemm5f(
    const float* __restrict__ z, const float* __restrict__ W5,
    float* __restrict__ out5, int base, int cnt, int N)
{
  __shared__ float Zs[64][65];
  __shared__ float Ws[64][41];
  int t = threadIdx.x;
  int lb = blockIdx.x*64;        // local row base within chunk
  int tx = t & 7;                // 8 col groups x 5 cols
  int ty = t >> 3;               // 32 row groups x 2 rows
  float acc[2][5] = {};
  for (int hc = 0; hc < 8; hc++){
    for (int i = t; i < 64*16; i += 256){
      int n = i >> 4, kq = i & 15;
      float4 v = make_float4(0.f,0.f,0.f,0.f);
      int lnn = lb + n;
      if (lnn < cnt) v = *(const float4*)(z + (size_t)lnn*512 + hc*64 + kq*4);
      Zs[n][kq*4+0]=v.x; Zs[n][kq*4+1]=v.y; Zs[n][kq*4+2]=v.z; Zs[n][kq*4+3]=v.w;
    }
    for (int i = t; i < 64*40; i += 256){
      int k = i/40, c = i - k*40;
      Ws[k][c] = W5[(size_t)k*320 + hc*40 + c];
    }
    __syncthreads();
    #pragma unroll 4
    for (int k=0;k<64;k++){
      float a0 = Zs[ty*2+0][k], a1 = Zs[ty*2+1][k];
      float w0=Ws[k][tx*5+0], w1=Ws[k][tx*5+1], w2=Ws[k][tx*5+2], w3=Ws[k][tx*5+3], w4=Ws[k][tx*5+4];
      acc[0][0]=fmaf(a0,w0,acc[0][0]); acc[0][1]=fmaf(a0,w1,acc[0][1]);
      acc[0][2]=fmaf(a0,w2,acc[0][2]); acc[0][3]=fmaf(a0,w3,acc[0][3]);
      acc[0][4]=fmaf(a0,w4,acc[0][4]);
      acc[1][0]=fmaf(a1,w0,acc[1][0]); acc[1][1]=fmaf(a1,w1,acc[1][1]);
      acc[1][2]=fmaf(a1,w2,acc[1][2]); acc[1][3]=fmaf(a1,w3,acc[1][3]);
      acc[1][4]=fmaf(a1,w4,acc[1][4]);
    }
    __syncthreads();
  }
  #pragma unroll
  for (int r=0;r<2;r++){
    int gn = base + lb + ty*2 + r;
    if (lb + ty*2 + r < cnt && gn < N){
      float* op = out5 + (size_t)gn*40 + tx*5;
      op[0]=acc[r][0]; op[1]=acc[r][1]; op[2]=acc[r][2]; op[3]=acc[r][3]; op[4]=acc[r][4];
    }
  }
}

// ---------------- final: mean over heads + bias + log_softmax ----------------
__global__ __launch_bounds__(256) void k_final(
    const float* __restrict__ acc, const float* __restrict__ b5,
    float* __restrict__ out, int N)
{
  int t = threadIdx.x;
  int node = blockIdx.x*4 + (t >> 6);
  if (node >= N) return;
  int tl = t & 63;
  float v = (tl < 40) ? acc[(size_t)node*40 + tl]*0.125f + b5[tl] : -1e30f;
  float m = v;
  #pragma unroll
  for (int o=32;o;o>>=1) m = fmaxf(m, __shfl_xor(m, o, 64));
  float ex = (tl < 40) ? __expf(v - m) : 0.f;
  float s = ex;
  #pragma unroll
  for (int o=32;o;o>>=1) s += __shfl_xor(s, o, 64);
  if (tl < 40) out[(size_t)node*40 + tl] = (v - m) - __logf(s);
}

extern "C" void kernel_launch(void* const* d_in, const int* in_sizes, int n_in,
                              void* d_out, int out_size, void* d_ws, size_t ws_size,
                              hipStream_t stream) {
  const float* x  = (const float*)d_in[0];
  const int*   ei = (const int*)d_in[1];
  const int N = in_sizes[0] / 128;
  const int E = in_sizes[1] / 2;
  const int* esrc = ei;
  const int* edst = ei + E;
  const float* W1 = (const float*)d_in[2];
  const float* as1= (const float*)d_in[3];
  const float* ad1= (const float*)d_in[4];
  const float* b1 = (const float*)d_in[5];
  const float* W2 = (const float*)d_in[6];
  const float* as2= (const float*)d_in[7];
  const float* ad2= (const float*)d_in[8];
  const float* b2 = (const float*)d_in[9];
  const float* W3 = (const float*)d_in[10];
  const float* as3= (const float*)d_in[11];
  const float* ad3= (const float*)d_in[12];
  const float* b3 = (const float*)d_in[13];
  const float* W4 = (const float*)d_in[14];
  const float* as4= (const float*)d_in[15];
  const float* ad4= (const float*)d_in[16];
  const float* b4 = (const float*)d_in[17];
  const float* W5 = (const float*)d_in[18];
  const float* as5= (const float*)d_in[19];
  const float* ad5= (const float*)d_in[20];
  const float* b5 = (const float*)d_in[21];

  char* p = (char*)d_ws;
  auto alloc = [&](size_t bytes)->void*{
    uintptr_t u = (uintptr_t)p;
    u = (u + 255) & ~(uintptr_t)255;
    void* r = (void*)u;
    p = (char*)u + bytes;
    return r;
  };
  int* deg    = (int*)alloc((size_t)N*4);
  int* off    = (int*)alloc((size_t)(N+1)*4);
  int* cur    = (int*)alloc((size_t)N*4);
  int* srcs   = (int*)alloc((size_t)(E+N)*4);
  float* al_s = (float*)alloc((size_t)N*8*4);
  float* al_d = (float*)alloc((size_t)N*8*4);
  float* featB= (float*)alloc((size_t)N*64*4);
  float* featA= (float*)alloc((size_t)N*64*4);   // featA + hbuf contiguous: reused as z chunks
  float* hbuf = (float*)alloc((size_t)N*64*4);
  float* wsb  = (float*)alloc((size_t)8*64*4);
  float* wdb  = (float*)alloc((size_t)8*64*4);
  float* out5 = (float*)alloc((size_t)N*40*4);
  float* zbuf = featA;                           // 2*N*64*4 = 51.2MB >= 25000*512*4

  int gN = (N+255)/256, gE = (E+255)/256, gT = (N+63)/64, gA = (N+3)/4;
  int gA64 = (N+31)/32;

  // CSR
  k_init_deg<<<gN,256,0,stream>>>(deg, N);
  k_count  <<<gE,256,0,stream>>>(edst, E, deg);
  k_scan   <<<1,1024,0,stream>>>(deg, off, N);
  k_copy   <<<gN,256,0,stream>>>(off, cur, N);
  k_self   <<<gN,256,0,stream>>>(cur, srcs, N);
  k_scatter<<<gE,256,0,stream>>>(esrc, edst, E, cur, srcs);

  // Layer 1
  k_gemm<128,64><<<gT,256,0,stream>>>(x, W1, 64, 0, hbuf, N);
  k_al<<<(N*8+255)/256,256,0,stream>>>(hbuf, as1, ad1, al_s, al_d, N*8);
  k_agg64<<<gA64,256,0,stream>>>(hbuf, al_s, al_d, off, srcs, b1, featA, N, 1);

  // Layer 2
  k_gemm<64,64><<<gT,256,0,stream>>>(featA, W2, 64, 0, hbuf, N);
  k_al<<<(N*8+255)/256,256,0,stream>>>(hbuf, as2, ad2, al_s, al_d, N*8);
  k_agg64<<<gA64,256,0,stream>>>(hbuf, al_s, al_d, off, srcs, b2, featB, N, 1);

  // Layer 3
  k_gemm<64,64><<<gT,256,0,stream>>>(featB, W3, 64, 0, hbuf, N);
  k_al<<<(N*8+255)/256,256,0,stream>>>(hbuf, as3, ad3, al_s, al_d, N*8);
  k_agg64<<<gA64,256,0,stream>>>(hbuf, al_s, al_d, off, srcs, b3, featA, N, 1);

  // Layer 4
  k_gemm<64,64><<<gT,256,0,stream>>>(featA, W4, 64, 0, hbuf, N);
  k_al<<<(N*8+255)/256,256,0,stream>>>(hbuf, as4, ad4, al_s, al_d, N*8);
  k_agg64<<<gA64,256,0,stream>>>(hbuf, al_s, al_d, off, srcs, b4, featB, N, 1);

  // Layer 5: folded attn logits; chunked aggregate->z then GEMM (z overlays featA+hbuf)
  k_ws  <<<1,512,0,stream>>>(W5, as5, ad5, wsb, wdb);
  k_al5b<<<(N*8+255)/256,256,0,stream>>>(featB, wsb, wdb, al_s, al_d, N*8);
  const int CH = 25000;
  for (int base = 0; base < N; base += CH){
    int cnt = (N - base < CH) ? (N - base) : CH;
    k_agg5z<<<(cnt+3)/4,256,0,stream>>>(featB, al_s, al_d, off, srcs, zbuf, base, cnt);
    k_gemm5f<<<(cnt+63)/64,256,0,stream>>>(zbuf, W5, out5, base, cnt, N);
  }

  // mean + bias + log_softmax
  k_final<<<gA,256,0,stream>>>(out5, b5, (float*)d_out, N);
}

// Round 4
// 1104.219 us; speedup vs baseline: 3.8793x; 1.1507x over previous
//
#include <hip/hip_runtime.h>
#include <cstddef>
#include <cstdint>

static __device__ __forceinline__ float leaky(float x){ return x >= 0.f ? x : 0.2f*x; }

// ---------------- CSR build ----------------
__global__ void k_init_deg(int* __restrict__ deg, int N){
  int i = blockIdx.x*256 + threadIdx.x;
  if (i < N) deg[i] = 1;                      // self-loop
}
__global__ void k_count(const int* __restrict__ dst, int E, int* __restrict__ deg){
  int e = blockIdx.x*256 + threadIdx.x;
  if (e < E) atomicAdd(&deg[dst[e]], 1);
}
// hierarchical scan: per-block sums -> scan of block sums -> per-block offsets
__global__ __launch_bounds__(256) void k_bsum(const int* __restrict__ deg, int* __restrict__ bsum, int N){
  __shared__ int sm[256];
  int t = threadIdx.x; int i = blockIdx.x*256 + t;
  sm[t] = (i < N) ? deg[i] : 0;
  __syncthreads();
  #pragma unroll
  for (int o=128;o;o>>=1){ if (t<o) sm[t]+=sm[t+o]; __syncthreads(); }
  if (t==0) bsum[blockIdx.x] = sm[0];
}
__global__ __launch_bounds__(512) void k_bscan(const int* __restrict__ bsum, int* __restrict__ boff, int NB){
  __shared__ int sm[512];
  int t = threadIdx.x;
  int v = (t < NB) ? bsum[t] : 0;
  sm[t] = v; __syncthreads();
  for (int o=1;o<512;o<<=1){
    int u = (t>=o) ? sm[t-o] : 0;
    __syncthreads();
    sm[t] += u;
    __syncthreads();
  }
  if (t < NB) boff[t] = sm[t] - v;            // exclusive
  if (t == NB-1) boff[NB] = sm[t];            // total
}
__global__ __launch_bounds__(256) void k_off(const int* __restrict__ deg, const int* __restrict__ boff,
                                             int* __restrict__ off, int* __restrict__ cur, int N, int NB){
  __shared__ int sm[256];
  int t = threadIdx.x, b = blockIdx.x;
  int i = b*256 + t;
  int v = (i < N) ? deg[i] : 0;
  sm[t] = v; __syncthreads();
  for (int o=1;o<256;o<<=1){
    int u = (t>=o) ? sm[t-o] : 0;
    __syncthreads();
    sm[t] += u;
    __syncthreads();
  }
  if (i < N){ int e = boff[b] + sm[t] - v; off[i] = e; cur[i] = e; }
  if (b == 0 && t == 0) off[N] = boff[NB];
}
__global__ void k_self(int* __restrict__ cur, int* __restrict__ srcs, int N){
  int i = blockIdx.x*256 + threadIdx.x;
  if (i < N){ int p = atomicAdd(&cur[i],1); srcs[p] = i; }
}
__global__ void k_scatter(const int* __restrict__ src, const int* __restrict__ dst, int E,
                          int* __restrict__ cur, int* __restrict__ srcs){
  int e = blockIdx.x*256 + threadIdx.x;
  if (e < E){ int p = atomicAdd(&cur[dst[e]],1); srcs[p] = src[e]; }
}

// ---------------- GEMM: out[n, m] = A[n,:] @ W[:, col0+m] ----------------
template<int K, int M>
__global__ __launch_bounds__(256) void k_gemm(
    const float* __restrict__ A, const float* __restrict__ W, int ldw, int col0,
    float* __restrict__ out, int N)
{
  constexpr int KT = 64;
  constexpr int TX = M/4;
  __shared__ float As[64][KT+1];
  __shared__ alignas(16) float Ws[KT][M];
  int t = threadIdx.x;
  int base = blockIdx.x*64;
  int tx = t % TX, ty = t / TX;
  bool act = ty < 16;
  int n0 = ty*4, m0 = tx*4;
  float acc[4][4] = {};
  for (int kt=0; kt<K; kt+=KT){
    for (int i=t; i<64*(KT/4); i+=256){
      int n  = i >> 4;
      int kq = i & 15;
      float4 v = make_float4(0.f,0.f,0.f,0.f);
      int gn = base + n;
      if (gn < N) v = *(const float4*)(A + (size_t)gn*K + kt + kq*4);
      As[n][kq*4+0]=v.x; As[n][kq*4+1]=v.y; As[n][kq*4+2]=v.z; As[n][kq*4+3]=v.w;
    }
    for (int i=t; i<KT*(M/4); i+=256){
      int k = i/(M/4), mq = i%(M/4);
      *(float4*)&Ws[k][mq*4] = *(const float4*)(W + (size_t)(kt+k)*ldw + col0 + mq*4);
    }
    __syncthreads();
    if (act){
      #pragma unroll 8
      for (int k=0;k<KT;k++){
        float4 w = *(const float4*)&Ws[k][m0];
        float av0 = As[n0+0][k], av1 = As[n0+1][k], av2 = As[n0+2][k], av3 = As[n0+3][k];
        acc[0][0]=fmaf(av0,w.x,acc[0][0]); acc[0][1]=fmaf(av0,w.y,acc[0][1]);
        acc[0][2]=fmaf(av0,w.z,acc[0][2]); acc[0][3]=fmaf(av0,w.w,acc[0][3]);
        acc[1][0]=fmaf(av1,w.x,acc[1][0]); acc[1][1]=fmaf(av1,w.y,acc[1][1]);
        acc[1][2]=fmaf(av1,w.z,acc[1][2]); acc[1][3]=fmaf(av1,w.w,acc[1][3]);
        acc[2][0]=fmaf(av2,w.x,acc[2][0]); acc[2][1]=fmaf(av2,w.y,acc[2][1]);
        acc[2][2]=fmaf(av2,w.z,acc[2][2]); acc[2][3]=fmaf(av2,w.w,acc[2][3]);
        acc[3][0]=fmaf(av3,w.x,acc[3][0]); acc[3][1]=fmaf(av3,w.y,acc[3][1]);
        acc[3][2]=fmaf(av3,w.z,acc[3][2]); acc[3][3]=fmaf(av3,w.w,acc[3][3]);
      }
    }
    __syncthreads();
  }
  if (act){
    #pragma unroll
    for (int i=0;i<4;i++){
      int gn = base + n0 + i;
      if (gn < N){
        float4 v = make_float4(acc[i][0],acc[i][1],acc[i][2],acc[i][3]);
        *(float4*)(out + (size_t)gn*M + m0) = v;
      }
    }
  }
}

// ---------------- attention logits (layers 1-4, H=8, C=8) ----------------
__global__ void k_al(const float* __restrict__ h, const float* __restrict__ a_s,
                     const float* __restrict__ a_d, float* __restrict__ al_s,
                     float* __restrict__ al_d, int total /* N*8 */)
{
  int idx = blockIdx.x*256 + threadIdx.x;
  if (idx >= total) return;
  int hd = idx & 7;
  const float4* hp = (const float4*)(h + (size_t)idx*8);
  float4 h0 = hp[0], h1 = hp[1];
  const float4* sp = (const float4*)(a_s + hd*8);
  const float4* dp = (const float4*)(a_d + hd*8);
  float4 s0 = sp[0], s1 = sp[1], d0 = dp[0], d1 = dp[1];
  al_s[idx] = h0.x*s0.x + h0.y*s0.y + h0.z*s0.z + h0.w*s0.w
            + h1.x*s1.x + h1.y*s1.y + h1.z*s1.z + h1.w*s1.w;
  al_d[idx] = h0.x*d0.x + h0.y*d0.y + h0.z*d0.z + h0.w*d0.w
            + h1.x*d1.x + h1.y*d1.y + h1.z*d1.z + h1.w*d1.w;
}

// ---------------- aggregation (layers 1-4): single-pass, 8 lanes per node ----------------
__global__ __launch_bounds__(256) void k_agg64(
    const float* __restrict__ h, const float* __restrict__ al_s,
    const float* __restrict__ al_d, const int* __restrict__ off,
    const int* __restrict__ srcs, const float* __restrict__ bias,
    float* __restrict__ outf, int N, int apply_act)
{
  int t = threadIdx.x;
  int grp = t >> 3;              // node within block
  int sub = t & 7;               // head / col-block
  int node = blockIdx.x*32 + grp;
  if (node >= N) return;
  int beg = off[node], end = off[node+1];
  float ald = al_d[(size_t)node*8 + sub];
  float s = 0.f;
  float acc[8] = {0.f,0.f,0.f,0.f,0.f,0.f,0.f,0.f};
  int j = beg;
  for (; j+3 < end; j += 4){
    int s0 = srcs[j], s1 = srcs[j+1], s2 = srcs[j+2], s3 = srcs[j+3];
    float e0 = leaky(al_s[(size_t)s0*8 + sub] + ald);
    float e1 = leaky(al_s[(size_t)s1*8 + sub] + ald);
    float e2 = leaky(al_s[(size_t)s2*8 + sub] + ald);
    float e3 = leaky(al_s[(size_t)s3*8 + sub] + ald);
    float a0 = __expf(e0), a1 = __expf(e1), a2 = __expf(e2), a3 = __expf(e3);
    const float4* f0 = (const float4*)(h + (size_t)s0*64 + sub*8);
    const float4* f1 = (const float4*)(h + (size_t)s1*64 + sub*8);
    const float4* f2 = (const float4*)(h + (size_t)s2*64 + sub*8);
    const float4* f3 = (const float4*)(h + (size_t)s3*64 + sub*8);
    float4 u0 = f0[0], u1 = f0[1];
    float4 v0 = f1[0], v1 = f1[1];
    float4 w0 = f2[0], w1 = f2[1];
    float4 x0 = f3[0], x1 = f3[1];
    s += a0 + a1 + a2 + a3;
    acc[0]=fmaf(a0,u0.x,acc[0]); acc[1]=fmaf(a0,u0.y,acc[1]);
    acc[2]=fmaf(a0,u0.z,acc[2]); acc[3]=fmaf(a0,u0.w,acc[3]);
    acc[4]=fmaf(a0,u1.x,acc[4]); acc[5]=fmaf(a0,u1.y,acc[5]);
    acc[6]=fmaf(a0,u1.z,acc[6]); acc[7]=fmaf(a0,u1.w,acc[7]);
    acc[0]=fmaf(a1,v0.x,acc[0]); acc[1]=fmaf(a1,v0.y,acc[1]);
    acc[2]=fmaf(a1,v0.z,acc[2]); acc[3]=fmaf(a1,v0.w,acc[3]);
    acc[4]=fmaf(a1,v1.x,acc[4]); acc[5]=fmaf(a1,v1.y,acc[5]);
    acc[6]=fmaf(a1,v1.z,acc[6]); acc[7]=fmaf(a1,v1.w,acc[7]);
    acc[0]=fmaf(a2,w0.x,acc[0]); acc[1]=fmaf(a2,w0.y,acc[1]);
    acc[2]=fmaf(a2,w0.z,acc[2]); acc[3]=fmaf(a2,w0.w,acc[3]);
    acc[4]=fmaf(a2,w1.x,acc[4]); acc[5]=fmaf(a2,w1.y,acc[5]);
    acc[6]=fmaf(a2,w1.z,acc[6]); acc[7]=fmaf(a2,w1.w,acc[7]);
    acc[0]=fmaf(a3,x0.x,acc[0]); acc[1]=fmaf(a3,x0.y,acc[1]);
    acc[2]=fmaf(a3,x0.z,acc[2]); acc[3]=fmaf(a3,x0.w,acc[3]);
    acc[4]=fmaf(a3,x1.x,acc[4]); acc[5]=fmaf(a3,x1.y,acc[5]);
    acc[6]=fmaf(a3,x1.z,acc[6]); acc[7]=fmaf(a3,x1.w,acc[7]);
  }
  for (; j < end; ++j){
    int s0 = srcs[j];
    float e0 = leaky(al_s[(size_t)s0*8 + sub] + ald);
    float a0 = __expf(e0);
    const float4* f0 = (const float4*)(h + (size_t)s0*64 + sub*8);
    float4 u0 = f0[0], u1 = f0[1];
    s += a0;
    acc[0]=fmaf(a0,u0.x,acc[0]); acc[1]=fmaf(a0,u0.y,acc[1]);
    acc[2]=fmaf(a0,u0.z,acc[2]); acc[3]=fmaf(a0,u0.w,acc[3]);
    acc[4]=fmaf(a0,u1.x,acc[4]); acc[5]=fmaf(a0,u1.y,acc[5]);
    acc[6]=fmaf(a0,u1.z,acc[6]); acc[7]=fmaf(a0,u1.w,acc[7]);
  }
  float inv = 1.f/(s + 1e-16f);
  const float4* bp = (const float4*)(bias + sub*8);
  float4 b0 = bp[0], b1 = bp[1];
  float4 o0, o1;
  o0.x = acc[0]*inv + b0.x; o0.y = acc[1]*inv + b0.y;
  o0.z = acc[2]*inv + b0.z; o0.w = acc[3]*inv + b0.w;
  o1.x = acc[4]*inv + b1.x; o1.y = acc[5]*inv + b1.y;
  o1.z = acc[6]*inv + b1.z; o1.w = acc[7]*inv + b1.w;
  if (apply_act){
    o0.x = leaky(o0.x); o0.y = leaky(o0.y); o0.z = leaky(o0.z); o0.w = leaky(o0.w);
    o1.x = leaky(o1.x); o1.y = leaky(o1.y); o1.z = leaky(o1.z); o1.w = leaky(o1.w);
  }
  float* op = outf + (size_t)node*64 + sub*8;
  *(float4*)op = o0; *(float4*)(op+4) = o1;
}

// ---------------- layer 5: folded attention vectors ----------------
__global__ __launch_bounds__(512) void k_ws(const float* __restrict__ W5,
                                            const float* __restrict__ as5,
                                            const float* __restrict__ ad5,
                                            float* __restrict__ ws, float* __restrict__ wd){
  int t = threadIdx.x;
  int h = t >> 6, k = t & 63;
  float s = 0.f, d = 0.f;
  #pragma unroll 8
  for (int c=0;c<40;c++){
    float w = W5[(size_t)k*320 + h*40 + c];
    s = fmaf(w, as5[h*40+c], s);
    d = fmaf(w, ad5[h*40+c], d);
  }
  ws[h*64+k] = s; wd[h*64+k] = d;
}

// Wf[h*64+k][c] = W5[k][h*40+c]  (512 x 40)
__global__ void k_wf(const float* __restrict__ W5, float* __restrict__ Wf){
  int i = blockIdx.x*256 + threadIdx.x;
  if (i >= 512*40) return;
  int row = i / 40, c = i - row*40;
  int h = row >> 6, k = row & 63;
  Wf[i] = W5[(size_t)k*320 + h*40 + c];
}

__global__ void k_al5b(const float* __restrict__ feat, const float* __restrict__ ws,
                       const float* __restrict__ wd, float* __restrict__ al_s,
                       float* __restrict__ al_d, int total /* N*8 */)
{
  int idx = blockIdx.x*256 + threadIdx.x;
  if (idx >= total) return;
  int n = idx >> 3, h = idx & 7;
  const float4* fp = (const float4*)(feat + (size_t)n*64);
  const float4* ap = (const float4*)(ws + h*64);
  const float4* bp = (const float4*)(wd + h*64);
  float s = 0.f, d = 0.f;
  #pragma unroll
  for (int q=0;q<16;q++){
    float4 f = fp[q], a = ap[q], b = bp[q];
    s += f.x*a.x + f.y*a.y + f.z*a.z + f.w*a.w;
    d += f.x*b.x + f.y*b.y + f.z*b.z + f.w*b.w;
  }
  al_s[idx] = s; al_d[idx] = d;
}

// ---------------- layer 5 aggregation in input space -> z[local_n][h*64+k] ----------------
__global__ __launch_bounds__(256) void k_agg5z(
    const float* __restrict__ feat, const float* __restrict__ al_s,
    const float* __restrict__ al_d, const int* __restrict__ off,
    const int* __restrict__ srcs, float* __restrict__ z, int base, int cnt)
{
  int t = threadIdx.x;
  int w = t >> 6;
  int ln = blockIdx.x*4 + w;
  if (ln >= cnt) return;
  int node = base + ln;
  int tl = t & 63;
  int hd = tl & 7;
  int cb = tl >> 3;
  int beg = off[node], end = off[node+1];
  float ald = al_d[(size_t)node*8 + hd];
  int lanebase = hd*4;
  int cbo = cb*8;
  float s = 0.f;
  float acc[8] = {0.f,0.f,0.f,0.f,0.f,0.f,0.f,0.f};
  for (int jb = beg; jb < end; jb += 8){
    int j = jb + cb;
    float atil = 0.f; int si = 0;
    if (j < end){
      si = srcs[j];
      atil = __expf(leaky(al_s[(size_t)si*8 + hd] + ald));
    }
    s += atil;
    #pragma unroll 8
    for (int e = 0; e < 8; e++){
      if (jb + e >= end) break;
      float ae = __uint_as_float(__builtin_amdgcn_ds_bpermute(lanebase + e*32, __float_as_uint(atil)));
      int sie = __builtin_amdgcn_readlane(si, e*8);
      const float4* fp = (const float4*)(feat + (size_t)sie*64 + cbo);
      float4 v0 = fp[0], v1 = fp[1];
      acc[0]=fmaf(ae,v0.x,acc[0]); acc[1]=fmaf(ae,v0.y,acc[1]);
      acc[2]=fmaf(ae,v0.z,acc[2]); acc[3]=fmaf(ae,v0.w,acc[3]);
      acc[4]=fmaf(ae,v1.x,acc[4]); acc[5]=fmaf(ae,v1.y,acc[5]);
      acc[6]=fmaf(ae,v1.z,acc[6]); acc[7]=fmaf(ae,v1.w,acc[7]);
    }
  }
  s += __shfl_xor(s, 8, 64);
  s += __shfl_xor(s, 16, 64);
  s += __shfl_xor(s, 32, 64);
  float inv = 1.f/(s + 1e-16f);
  float4 o0 = make_float4(acc[0]*inv, acc[1]*inv, acc[2]*inv, acc[3]*inv);
  float4 o1 = make_float4(acc[4]*inv, acc[5]*inv, acc[6]*inv, acc[7]*inv);
  float* zp = z + (size_t)ln*512 + hd*64 + cbo;
  *(float4*)zp = o0; *(float4*)(zp+4) = o1;
}

// ---------------- final: mean over heads + bias + log_softmax ----------------
__global__ __launch_bounds__(256) void k_final(
    const float* __restrict__ acc, const float* __restrict__ b5,
    float* __restrict__ out, int N)
{
  int t = threadIdx.x;
  int node = blockIdx.x*4 + (t >> 6);
  if (node >= N) return;
  int tl = t & 63;
  float v = (tl < 40) ? acc[(size_t)node*40 + tl]*0.125f + b5[tl] : -1e30f;
  float m = v;
  #pragma unroll
  for (int o=32;o;o>>=1) m = fmaxf(m, __shfl_xor(m, o, 64));
  float ex = (tl < 40) ? __expf(v - m) : 0.f;
  float s = ex;
  #pragma unroll
  for (int o=32;o;o>>=1) s += __shfl_xor(s, o, 64);
  if (tl < 40) out[(size_t)node*40 + tl] = (v - m) - __logf(s);
}

extern "C" void kernel_launch(void* const* d_in, const int* in_sizes, int n_in,
                              void* d_out, int out_size, void* d_ws, size_t ws_size,
                              hipStream_t stream) {
  const float* x  = (const float*)d_in[0];
  const int*   ei = (const int*)d_in[1];
  const int N = in_sizes[0] / 128;
  const int E = in_sizes[1] / 2;
  const int* esrc = ei;
  const int* edst = ei + E;
  const float* W1 = (const float*)d_in[2];
  const float* as1= (const float*)d_in[3];
  const float* ad1= (const float*)d_in[4];
  const float* b1 = (const float*)d_in[5];
  const float* W2 = (const float*)d_in[6];
  const float* as2= (const float*)d_in[7];
  const float* ad2= (const float*)d_in[8];
  const float* b2 = (const float*)d_in[9];
  const float* W3 = (const float*)d_in[10];
  const float* as3= (const float*)d_in[11];
  const float* ad3= (const float*)d_in[12];
  const float* b3 = (const float*)d_in[13];
  const float* W4 = (const float*)d_in[14];
  const float* as4= (const float*)d_in[15];
  const float* ad4= (const float*)d_in[16];
  const float* b4 = (const float*)d_in[17];
  const float* W5 = (const float*)d_in[18];
  const float* as5= (const float*)d_in[19];
  const float* ad5= (const float*)d_in[20];
  const float* b5 = (const float*)d_in[21];

  char* p = (char*)d_ws;
  auto alloc = [&](size_t bytes)->void*{
    uintptr_t u = (uintptr_t)p;
    u = (u + 255) & ~(uintptr_t)255;
    void* r = (void*)u;
    p = (char*)u + bytes;
    return r;
  };
  int NB = (N + 255)/256;                        // 391 for N=100000 (must be <=512)
  int* deg    = (int*)alloc((size_t)N*4);
  int* off    = (int*)alloc((size_t)(N+1)*4);
  int* cur    = (int*)alloc((size_t)N*4);
  int* bsum   = (int*)alloc((size_t)NB*4);
  int* boff   = (int*)alloc((size_t)(NB+1)*4);
  int* srcs   = (int*)alloc((size_t)(E+N)*4);
  float* al_s = (float*)alloc((size_t)N*8*4);
  float* al_d = (float*)alloc((size_t)N*8*4);
  float* featB= (float*)alloc((size_t)N*64*4);
  float* featA= (float*)alloc((size_t)N*64*4);   // featA + hbuf contiguous: reused as z chunks
  float* hbuf = (float*)alloc((size_t)N*64*4);
  float* wsb  = (float*)alloc((size_t)8*64*4);
  float* wdb  = (float*)alloc((size_t)8*64*4);
  float* Wf   = (float*)alloc((size_t)512*40*4);
  float* out5 = (float*)alloc((size_t)N*40*4);
  float* zbuf = featA;                           // 2*N*64*4 = 51.2MB >= 25000*512*4

  int gN = (N+255)/256, gE = (E+255)/256, gT = (N+63)/64, gA = (N+3)/4;
  int gA64 = (N+31)/32;

  // CSR
  k_init_deg<<<gN,256,0,stream>>>(deg, N);
  k_count  <<<gE,256,0,stream>>>(edst, E, deg);
  k_bsum   <<<NB,256,0,stream>>>(deg, bsum, N);
  k_bscan  <<<1,512,0,stream>>>(bsum, boff, NB);
  k_off    <<<NB,256,0,stream>>>(deg, boff, off, cur, N, NB);
  k_self   <<<gN,256,0,stream>>>(cur, srcs, N);
  k_scatter<<<gE,256,0,stream>>>(esrc, edst, E, cur, srcs);

  // Layer 1
  k_gemm<128,64><<<gT,256,0,stream>>>(x, W1, 64, 0, hbuf, N);
  k_al<<<(N*8+255)/256,256,0,stream>>>(hbuf, as1, ad1, al_s, al_d, N*8);
  k_agg64<<<gA64,256,0,stream>>>(hbuf, al_s, al_d, off, srcs, b1, featA, N, 1);

  // Layer 2
  k_gemm<64,64><<<gT,256,0,stream>>>(featA, W2, 64, 0, hbuf, N);
  k_al<<<(N*8+255)/256,256,0,stream>>>(hbuf, as2, ad2, al_s, al_d, N*8);
  k_agg64<<<gA64,256,0,stream>>>(hbuf, al_s, al_d, off, srcs, b2, featB, N, 1);

  // Layer 3
  k_gemm<64,64><<<gT,256,0,stream>>>(featB, W3, 64, 0, hbuf, N);
  k_al<<<(N*8+255)/256,256,0,stream>>>(hbuf, as3, ad3, al_s, al_d, N*8);
  k_agg64<<<gA64,256,0,stream>>>(hbuf, al_s, al_d, off, srcs, b3, featA, N, 1);

  // Layer 4
  k_gemm<64,64><<<gT,256,0,stream>>>(featA, W4, 64, 0, hbuf, N);
  k_al<<<(N*8+255)/256,256,0,stream>>>(hbuf, as4, ad4, al_s, al_d, N*8);
  k_agg64<<<gA64,256,0,stream>>>(hbuf, al_s, al_d, off, srcs, b4, featB, N, 1);

  // Layer 5: folded attn logits; chunked aggregate->z then tiled GEMM z@Wf
  k_ws  <<<1,512,0,stream>>>(W5, as5, ad5, wsb, wdb);
  k_wf  <<<(512*40+255)/256,256,0,stream>>>(W5, Wf);
  k_al5b<<<(N*8+255)/256,256,0,stream>>>(featB, wsb, wdb, al_s, al_d, N*8);
  const int CH = 25000;
  for (int base = 0; base < N; base += CH){
    int cnt = (N - base < CH) ? (N - base) : CH;
    k_agg5z<<<(cnt+3)/4,256,0,stream>>>(featB, al_s, al_d, off, srcs, zbuf, base, cnt);
    k_gemm<512,40><<<(cnt+63)/64,256,0,stream>>>(zbuf, Wf, 40, 0, out5 + (size_t)base*40, cnt);
  }

  // mean + bias + log_softmax
  k_final<<<gA,256,0,stream>>>(out5, b5, (float*)d_out, N);
}

// Round 5
// 954.090 us; speedup vs baseline: 4.4897x; 1.1574x over previous
//
#include <hip/hip_runtime.h>
#include <cstddef>
#include <cstdint>

static __device__ __forceinline__ float leaky(float x){ return x >= 0.f ? x : 0.2f*x; }

// ---------------- CSR build: atomic-free MSD bucket sort ----------------
// pass 1: histogram of dst>>8 per block (512 bins x NBLK blocks)
__global__ __launch_bounds__(256) void rs_hist1(const int* __restrict__ edst, int E, int N,
                                                int* __restrict__ hist, int NBLK, int Etot){
  __shared__ int lh[512];
  int t = threadIdx.x, b = blockIdx.x;
  lh[t] = 0; lh[t+256] = 0;
  __syncthreads();
  int base = b*8192;
  for (int i = 0; i < 32; i++){
    int e = base + t + i*256;
    if (e < Etot){
      int d = (e < E) ? edst[e] : (e - E);
      atomicAdd(&lh[d>>8], 1);
    }
  }
  __syncthreads();
  hist[(size_t)t*NBLK + b] = lh[t];
  hist[(size_t)(t+256)*NBLK + b] = lh[t+256];
}

// generic hierarchical exclusive scan over L ints (L <= 512*256)
__global__ __launch_bounds__(256) void s_bsum(const int* __restrict__ a, int* __restrict__ bsum, int L){
  __shared__ int sm[256];
  int t = threadIdx.x; int i = blockIdx.x*256 + t;
  sm[t] = (i < L) ? a[i] : 0;
  __syncthreads();
  #pragma unroll
  for (int o=128;o;o>>=1){ if (t<o) sm[t]+=sm[t+o]; __syncthreads(); }
  if (t==0) bsum[blockIdx.x] = sm[0];
}
__global__ __launch_bounds__(512) void k_bscan(const int* __restrict__ bsum, int* __restrict__ boff, int NB){
  __shared__ int sm[512];
  int t = threadIdx.x;
  int v = (t < NB) ? bsum[t] : 0;
  sm[t] = v; __syncthreads();
  for (int o=1;o<512;o<<=1){
    int u = (t>=o) ? sm[t-o] : 0;
    __syncthreads();
    sm[t] += u;
    __syncthreads();
  }
  if (t < NB) boff[t] = sm[t] - v;            // exclusive
  if (t == NB-1) boff[NB] = sm[t];            // total
}
__global__ __launch_bounds__(256) void s_apply(const int* __restrict__ a, const int* __restrict__ boff,
                                               int* __restrict__ out, int L){
  __shared__ int sm[256];
  int t = threadIdx.x, b = blockIdx.x;
  int i = b*256 + t;
  int v = (i < L) ? a[i] : 0;
  sm[t] = v; __syncthreads();
  for (int o=1;o<256;o<<=1){
    int u = (t>=o) ? sm[t-o] : 0;
    __syncthreads();
    sm[t] += u;
    __syncthreads();
  }
  if (i < L) out[i] = boff[b] + sm[t] - v;    // exclusive
}

// pass 1 scatter: place (src,dst) into coarse-group-sorted bufA. LDS atomics only.
__global__ __launch_bounds__(256) void rs_scatter1(const int* __restrict__ esrc, const int* __restrict__ edst,
                                                   int E, int N, const int* __restrict__ hist2, int NBLK,
                                                   int2* __restrict__ bufA, int Etot){
  __shared__ int gb[512];
  __shared__ int lcnt[512];
  int t = threadIdx.x, b = blockIdx.x;
  gb[t]     = hist2[(size_t)t*NBLK + b];
  gb[t+256] = hist2[(size_t)(t+256)*NBLK + b];
  lcnt[t] = 0; lcnt[t+256] = 0;
  __syncthreads();
  int base = b*8192;
  for (int i = 0; i < 32; i++){
    int e = base + t + i*256;
    if (e < Etot){
      int s, d;
      if (e < E){ s = esrc[e]; d = edst[e]; }
      else { s = e - E; d = s; }
      int bin = d >> 8;
      int r = atomicAdd(&lcnt[bin], 1);
      bufA[gb[bin] + r] = make_int2(s, d);
    }
  }
}

// pass 2: per coarse group (256 nodes), counting-sort by dst&255; emit srcs + off.
__global__ __launch_bounds__(256) void rs_lvl2(const int2* __restrict__ bufA, const int* __restrict__ hist2,
                                               int NBLK, int* __restrict__ srcs, int* __restrict__ off,
                                               int N, int Etot){
  __shared__ int cnt[256];
  __shared__ int basev[256];
  int t = threadIdx.x, g = blockIdx.x;
  int beg = hist2[(size_t)g*NBLK];
  int end = (g < 511) ? hist2[(size_t)(g+1)*NBLK] : Etot;
  cnt[t] = 0;
  __syncthreads();
  for (int j = beg + t; j < end; j += 256)
    atomicAdd(&cnt[bufA[j].y & 255], 1);
  __syncthreads();
  int v = cnt[t];
  // inclusive scan in place
  for (int o=1;o<256;o<<=1){
    int u = (t>=o) ? cnt[t-o] : 0;
    __syncthreads();
    cnt[t] += u;
    __syncthreads();
  }
  basev[t] = cnt[t] - v;        // exclusive
  __syncthreads();
  cnt[t] = 0;                   // reuse as rank counter
  __syncthreads();
  for (int j = beg + t; j < end; j += 256){
    int2 p = bufA[j];
    int lb = p.y & 255;
    int r = atomicAdd(&cnt[lb], 1);
    srcs[beg + basev[lb] + r] = p.x;
  }
  int node = g*256 + t;
  if (node < N) off[node] = beg + basev[t];
  if (g == 0 && t == 0) off[N] = Etot;
}

// ---------------- GEMM: out[n, m] = A[n,:] @ W[:, col0+m] ----------------
template<int K, int M>
__global__ __launch_bounds__(256) void k_gemm(
    const float* __restrict__ A, const float* __restrict__ W, int ldw, int col0,
    float* __restrict__ out, int N)
{
  constexpr int KT = 64;
  constexpr int TX = M/4;
  __shared__ float As[64][KT+1];
  __shared__ alignas(16) float Ws[KT][M];
  int t = threadIdx.x;
  int base = blockIdx.x*64;
  int tx = t % TX, ty = t / TX;
  bool act = ty < 16;
  int n0 = ty*4, m0 = tx*4;
  float acc[4][4] = {};
  for (int kt=0; kt<K; kt+=KT){
    for (int i=t; i<64*(KT/4); i+=256){
      int n  = i >> 4;
      int kq = i & 15;
      float4 v = make_float4(0.f,0.f,0.f,0.f);
      int gn = base + n;
      if (gn < N) v = *(const float4*)(A + (size_t)gn*K + kt + kq*4);
      As[n][kq*4+0]=v.x; As[n][kq*4+1]=v.y; As[n][kq*4+2]=v.z; As[n][kq*4+3]=v.w;
    }
    for (int i=t; i<KT*(M/4); i+=256){
      int k = i/(M/4), mq = i%(M/4);
      *(float4*)&Ws[k][mq*4] = *(const float4*)(W + (size_t)(kt+k)*ldw + col0 + mq*4);
    }
    __syncthreads();
    if (act){
      #pragma unroll 8
      for (int k=0;k<KT;k++){
        float4 w = *(const float4*)&Ws[k][m0];
        float av0 = As[n0+0][k], av1 = As[n0+1][k], av2 = As[n0+2][k], av3 = As[n0+3][k];
        acc[0][0]=fmaf(av0,w.x,acc[0][0]); acc[0][1]=fmaf(av0,w.y,acc[0][1]);
        acc[0][2]=fmaf(av0,w.z,acc[0][2]); acc[0][3]=fmaf(av0,w.w,acc[0][3]);
        acc[1][0]=fmaf(av1,w.x,acc[1][0]); acc[1][1]=fmaf(av1,w.y,acc[1][1]);
        acc[1][2]=fmaf(av1,w.z,acc[1][2]); acc[1][3]=fmaf(av1,w.w,acc[1][3]);
        acc[2][0]=fmaf(av2,w.x,acc[2][0]); acc[2][1]=fmaf(av2,w.y,acc[2][1]);
        acc[2][2]=fmaf(av2,w.z,acc[2][2]); acc[2][3]=fmaf(av2,w.w,acc[2][3]);
        acc[3][0]=fmaf(av3,w.x,acc[3][0]); acc[3][1]=fmaf(av3,w.y,acc[3][1]);
        acc[3][2]=fmaf(av3,w.z,acc[3][2]); acc[3][3]=fmaf(av3,w.w,acc[3][3]);
      }
    }
    __syncthreads();
  }
  if (act){
    #pragma unroll
    for (int i=0;i<4;i++){
      int gn = base + n0 + i;
      if (gn < N){
        float4 v = make_float4(acc[i][0],acc[i][1],acc[i][2],acc[i][3]);
        *(float4*)(out + (size_t)gn*M + m0) = v;
      }
    }
  }
}

// ---------------- attention logits (layers 1-4, H=8, C=8) ----------------
__global__ void k_al(const float* __restrict__ h, const float* __restrict__ a_s,
                     const float* __restrict__ a_d, float* __restrict__ al_s,
                     float* __restrict__ al_d, int total /* N*8 */)
{
  int idx = blockIdx.x*256 + threadIdx.x;
  if (idx >= total) return;
  int hd = idx & 7;
  const float4* hp = (const float4*)(h + (size_t)idx*8);
  float4 h0 = hp[0], h1 = hp[1];
  const float4* sp = (const float4*)(a_s + hd*8);
  const float4* dp = (const float4*)(a_d + hd*8);
  float4 s0 = sp[0], s1 = sp[1], d0 = dp[0], d1 = dp[1];
  al_s[idx] = h0.x*s0.x + h0.y*s0.y + h0.z*s0.z + h0.w*s0.w
            + h1.x*s1.x + h1.y*s1.y + h1.z*s1.z + h1.w*s1.w;
  al_d[idx] = h0.x*d0.x + h0.y*d0.y + h0.z*d0.z + h0.w*d0.w
            + h1.x*d1.x + h1.y*d1.y + h1.z*d1.z + h1.w*d1.w;
}

// ---------------- aggregation (layers 1-4): single-pass, 8 lanes per node ----------------
__global__ __launch_bounds__(256) void k_agg64(
    const float* __restrict__ h, const float* __restrict__ al_s,
    const float* __restrict__ al_d, const int* __restrict__ off,
    const int* __restrict__ srcs, const float* __restrict__ bias,
    float* __restrict__ outf, int N, int apply_act)
{
  int t = threadIdx.x;
  int grp = t >> 3;              // node within block
  int sub = t & 7;               // head / col-block
  int node = blockIdx.x*32 + grp;
  if (node >= N) return;
  int beg = off[node], end = off[node+1];
  float ald = al_d[(size_t)node*8 + sub];
  float s = 0.f;
  float acc[8] = {0.f,0.f,0.f,0.f,0.f,0.f,0.f,0.f};
  int j = beg;
  for (; j+3 < end; j += 4){
    int s0 = srcs[j], s1 = srcs[j+1], s2 = srcs[j+2], s3 = srcs[j+3];
    float e0 = leaky(al_s[(size_t)s0*8 + sub] + ald);
    float e1 = leaky(al_s[(size_t)s1*8 + sub] + ald);
    float e2 = leaky(al_s[(size_t)s2*8 + sub] + ald);
    float e3 = leaky(al_s[(size_t)s3*8 + sub] + ald);
    float a0 = __expf(e0), a1 = __expf(e1), a2 = __expf(e2), a3 = __expf(e3);
    const float4* f0 = (const float4*)(h + (size_t)s0*64 + sub*8);
    const float4* f1 = (const float4*)(h + (size_t)s1*64 + sub*8);
    const float4* f2 = (const float4*)(h + (size_t)s2*64 + sub*8);
    const float4* f3 = (const float4*)(h + (size_t)s3*64 + sub*8);
    float4 u0 = f0[0], u1 = f0[1];
    float4 v0 = f1[0], v1 = f1[1];
    float4 w0 = f2[0], w1 = f2[1];
    float4 x0 = f3[0], x1 = f3[1];
    s += a0 + a1 + a2 + a3;
    acc[0]=fmaf(a0,u0.x,acc[0]); acc[1]=fmaf(a0,u0.y,acc[1]);
    acc[2]=fmaf(a0,u0.z,acc[2]); acc[3]=fmaf(a0,u0.w,acc[3]);
    acc[4]=fmaf(a0,u1.x,acc[4]); acc[5]=fmaf(a0,u1.y,acc[5]);
    acc[6]=fmaf(a0,u1.z,acc[6]); acc[7]=fmaf(a0,u1.w,acc[7]);
    acc[0]=fmaf(a1,v0.x,acc[0]); acc[1]=fmaf(a1,v0.y,acc[1]);
    acc[2]=fmaf(a1,v0.z,acc[2]); acc[3]=fmaf(a1,v0.w,acc[3]);
    acc[4]=fmaf(a1,v1.x,acc[4]); acc[5]=fmaf(a1,v1.y,acc[5]);
    acc[6]=fmaf(a1,v1.z,acc[6]); acc[7]=fmaf(a1,v1.w,acc[7]);
    acc[0]=fmaf(a2,w0.x,acc[0]); acc[1]=fmaf(a2,w0.y,acc[1]);
    acc[2]=fmaf(a2,w0.z,acc[2]); acc[3]=fmaf(a2,w0.w,acc[3]);
    acc[4]=fmaf(a2,w1.x,acc[4]); acc[5]=fmaf(a2,w1.y,acc[5]);
    acc[6]=fmaf(a2,w1.z,acc[6]); acc[7]=fmaf(a2,w1.w,acc[7]);
    acc[0]=fmaf(a3,x0.x,acc[0]); acc[1]=fmaf(a3,x0.y,acc[1]);
    acc[2]=fmaf(a3,x0.z,acc[2]); acc[3]=fmaf(a3,x0.w,acc[3]);
    acc[4]=fmaf(a3,x1.x,acc[4]); acc[5]=fmaf(a3,x1.y,acc[5]);
    acc[6]=fmaf(a3,x1.z,acc[6]); acc[7]=fmaf(a3,x1.w,acc[7]);
  }
  for (; j < end; ++j){
    int s0 = srcs[j];
    float e0 = leaky(al_s[(size_t)s0*8 + sub] + ald);
    float a0 = __expf(e0);
    const float4* f0 = (const float4*)(h + (size_t)s0*64 + sub*8);
    float4 u0 = f0[0], u1 = f0[1];
    s += a0;
    acc[0]=fmaf(a0,u0.x,acc[0]); acc[1]=fmaf(a0,u0.y,acc[1]);
    acc[2]=fmaf(a0,u0.z,acc[2]); acc[3]=fmaf(a0,u0.w,acc[3]);
    acc[4]=fmaf(a0,u1.x,acc[4]); acc[5]=fmaf(a0,u1.y,acc[5]);
    acc[6]=fmaf(a0,u1.z,acc[6]); acc[7]=fmaf(a0,u1.w,acc[7]);
  }
  float inv = 1.f/(s + 1e-16f);
  const float4* bp = (const float4*)(bias + sub*8);
  float4 b0 = bp[0], b1 = bp[1];
  float4 o0, o1;
  o0.x = acc[0]*inv + b0.x; o0.y = acc[1]*inv + b0.y;
  o0.z = acc[2]*inv + b0.z; o0.w = acc[3]*inv + b0.w;
  o1.x = acc[4]*inv + b1.x; o1.y = acc[5]*inv + b1.y;
  o1.z = acc[6]*inv + b1.z; o1.w = acc[7]*inv + b1.w;
  if (apply_act){
    o0.x = leaky(o0.x); o0.y = leaky(o0.y); o0.z = leaky(o0.z); o0.w = leaky(o0.w);
    o1.x = leaky(o1.x); o1.y = leaky(o1.y); o1.z = leaky(o1.z); o1.w = leaky(o1.w);
  }
  float* op = outf + (size_t)node*64 + sub*8;
  *(float4*)op = o0; *(float4*)(op+4) = o1;
}

// ---------------- layer 5: folded attention vectors ----------------
__global__ __launch_bounds__(512) void k_ws(const float* __restrict__ W5,
                                            const float* __restrict__ as5,
                                            const float* __restrict__ ad5,
                                            float* __restrict__ ws, float* __restrict__ wd){
  int t = threadIdx.x;
  int h = t >> 6, k = t & 63;
  float s = 0.f, d = 0.f;
  #pragma unroll 8
  for (int c=0;c<40;c++){
    float w = W5[(size_t)k*320 + h*40 + c];
    s = fmaf(w, as5[h*40+c], s);
    d = fmaf(w, ad5[h*40+c], d);
  }
  ws[h*64+k] = s; wd[h*64+k] = d;
}

// Wf[h*64+k][c] = W5[k][h*40+c]  (512 x 40)
__global__ void k_wf(const float* __restrict__ W5, float* __restrict__ Wf){
  int i = blockIdx.x*256 + threadIdx.x;
  if (i >= 512*40) return;
  int row = i / 40, c = i - row*40;
  int h = row >> 6, k = row & 63;
  Wf[i] = W5[(size_t)k*320 + h*40 + c];
}

__global__ void k_al5b(const float* __restrict__ feat, const float* __restrict__ ws,
                       const float* __restrict__ wd, float* __restrict__ al_s,
                       float* __restrict__ al_d, int total /* N*8 */)
{
  int idx = blockIdx.x*256 + threadIdx.x;
  if (idx >= total) return;
  int n = idx >> 3, h = idx & 7;
  const float4* fp = (const float4*)(feat + (size_t)n*64);
  const float4* ap = (const float4*)(ws + h*64);
  const float4* bp = (const float4*)(wd + h*64);
  float s = 0.f, d = 0.f;
  #pragma unroll
  for (int q=0;q<16;q++){
    float4 f = fp[q], a = ap[q], b = bp[q];
    s += f.x*a.x + f.y*a.y + f.z*a.z + f.w*a.w;
    d += f.x*b.x + f.y*b.y + f.z*b.z + f.w*b.w;
  }
  al_s[idx] = s; al_d[idx] = d;
}

// ---------------- layer 5 aggregation in input space -> z[local_n][h*64+k] ----------------
__global__ __launch_bounds__(256) void k_agg5z(
    const float* __restrict__ feat, const float* __restrict__ al_s,
    const float* __restrict__ al_d, const int* __restrict__ off,
    const int* __restrict__ srcs, float* __restrict__ z, int base, int cnt)
{
  int t = threadIdx.x;
  int w = t >> 6;
  int ln = blockIdx.x*4 + w;
  if (ln >= cnt) return;
  int node = base + ln;
  int tl = t & 63;
  int hd = tl & 7;
  int cb = tl >> 3;
  int beg = off[node], end = off[node+1];
  float ald = al_d[(size_t)node*8 + hd];
  int lanebase = hd*4;
  int cbo = cb*8;
  float s = 0.f;
  float acc[8] = {0.f,0.f,0.f,0.f,0.f,0.f,0.f,0.f};
  for (int jb = beg; jb < end; jb += 8){
    int j = jb + cb;
    float atil = 0.f; int si = 0;
    if (j < end){
      si = srcs[j];
      atil = __expf(leaky(al_s[(size_t)si*8 + hd] + ald));
    }
    s += atil;
    #pragma unroll 8
    for (int e = 0; e < 8; e++){
      if (jb + e >= end) break;
      float ae = __uint_as_float(__builtin_amdgcn_ds_bpermute(lanebase + e*32, __float_as_uint(atil)));
      int sie = __builtin_amdgcn_readlane(si, e*8);
      const float4* fp = (const float4*)(feat + (size_t)sie*64 + cbo);
      float4 v0 = fp[0], v1 = fp[1];
      acc[0]=fmaf(ae,v0.x,acc[0]); acc[1]=fmaf(ae,v0.y,acc[1]);
      acc[2]=fmaf(ae,v0.z,acc[2]); acc[3]=fmaf(ae,v0.w,acc[3]);
      acc[4]=fmaf(ae,v1.x,acc[4]); acc[5]=fmaf(ae,v1.y,acc[5]);
      acc[6]=fmaf(ae,v1.z,acc[6]); acc[7]=fmaf(ae,v1.w,acc[7]);
    }
  }
  s += __shfl_xor(s, 8, 64);
  s += __shfl_xor(s, 16, 64);
  s += __shfl_xor(s, 32, 64);
  float inv = 1.f/(s + 1e-16f);
  float4 o0 = make_float4(acc[0]*inv, acc[1]*inv, acc[2]*inv, acc[3]*inv);
  float4 o1 = make_float4(acc[4]*inv, acc[5]*inv, acc[6]*inv, acc[7]*inv);
  float* zp = z + (size_t)ln*512 + hd*64 + cbo;
  *(float4*)zp = o0; *(float4*)(zp+4) = o1;
}

// ---------------- final: mean over heads + bias + log_softmax ----------------
__global__ __launch_bounds__(256) void k_final(
    const float* __restrict__ acc, const float* __restrict__ b5,
    float* __restrict__ out, int N)
{
  int t = threadIdx.x;
  int node = blockIdx.x*4 + (t >> 6);
  if (node >= N) return;
  int tl = t & 63;
  float v = (tl < 40) ? acc[(size_t)node*40 + tl]*0.125f + b5[tl] : -1e30f;
  float m = v;
  #pragma unroll
  for (int o=32;o;o>>=1) m = fmaxf(m, __shfl_xor(m, o, 64));
  float ex = (tl < 40) ? __expf(v - m) : 0.f;
  float s = ex;
  #pragma unroll
  for (int o=32;o;o>>=1) s += __shfl_xor(s, o, 64);
  if (tl < 40) out[(size_t)node*40 + tl] = (v - m) - __logf(s);
}

extern "C" void kernel_launch(void* const* d_in, const int* in_sizes, int n_in,
                              void* d_out, int out_size, void* d_ws, size_t ws_size,
                              hipStream_t stream) {
  const float* x  = (const float*)d_in[0];
  const int*   ei = (const int*)d_in[1];
  const int N = in_sizes[0] / 128;
  const int E = in_sizes[1] / 2;
  const int* esrc = ei;
  const int* edst = ei + E;
  const float* W1 = (const float*)d_in[2];
  const float* as1= (const float*)d_in[3];
  const float* ad1= (const float*)d_in[4];
  const float* b1 = (const float*)d_in[5];
  const float* W2 = (const float*)d_in[6];
  const float* as2= (const float*)d_in[7];
  const float* ad2= (const float*)d_in[8];
  const float* b2 = (const float*)d_in[9];
  const float* W3 = (const float*)d_in[10];
  const float* as3= (const float*)d_in[11];
  const float* ad3= (const float*)d_in[12];
  const float* b3 = (const float*)d_in[13];
  const float* W4 = (const float*)d_in[14];
  const float* as4= (const float*)d_in[15];
  const float* ad4= (const float*)d_in[16];
  const float* b4 = (const float*)d_in[17];
  const float* W5 = (const float*)d_in[18];
  const float* as5= (const float*)d_in[19];
  const float* ad5= (const float*)d_in[20];
  const float* b5 = (const float*)d_in[21];

  char* p = (char*)d_ws;
  auto alloc = [&](size_t bytes)->void*{
    uintptr_t u = (uintptr_t)p;
    u = (u + 255) & ~(uintptr_t)255;
    void* r = (void*)u;
    p = (char*)u + bytes;
    return r;
  };
  const int Etot = E + N;
  const int NBLK = (Etot + 8191)/8192;           // 208 for E'=1.7M (must be <=256)
  const int L    = 512*NBLK;                     // hist length
  const int NB2  = (L + 255)/256;                // <=512
  const int NG   = (N + 255)/256;                // 391 coarse groups (<=512)

  int* off    = (int*)alloc((size_t)(N+1)*4);
  int* srcs   = (int*)alloc((size_t)Etot*4);
  int* hist   = (int*)alloc((size_t)L*4);
  int* hist2  = (int*)alloc((size_t)L*4);
  int* hb     = (int*)alloc((size_t)(NB2+1)*4);
  float* al_s = (float*)alloc((size_t)N*8*4);
  float* al_d = (float*)alloc((size_t)N*8*4);
  float* featB= (float*)alloc((size_t)N*64*4);
  float* featA= (float*)alloc((size_t)N*64*4);   // featA + hbuf contiguous: reused as z chunks
  float* hbuf = (float*)alloc((size_t)N*64*4);
  float* wsb  = (float*)alloc((size_t)8*64*4);
  float* wdb  = (float*)alloc((size_t)8*64*4);
  float* Wf   = (float*)alloc((size_t)512*40*4);
  float* out5 = (float*)alloc((size_t)N*40*4);
  float* zbuf = featA;                           // 2*N*64*4 = 51.2MB >= 25000*512*4
  int2* bufA  = (int2*)featA;                    // sort scratch, dead before features exist

  int gN = (N+255)/256, gT = (N+63)/64, gA = (N+3)/4;
  int gA64 = (N+31)/32;

  // CSR: atomic-free two-level bucket sort (self-loops synthesized)
  rs_hist1  <<<NBLK,256,0,stream>>>(edst, E, N, hist, NBLK, Etot);
  s_bsum    <<<NB2,256,0,stream>>>(hist, hb, L);
  k_bscan   <<<1,512,0,stream>>>(hb, hb, NB2);   // in-place: boff aliases bsum (read then overwrite same slot)
  s_apply   <<<NB2,256,0,stream>>>(hist, hb, hist2, L);
  rs_scatter1<<<NBLK,256,0,stream>>>(esrc, edst, E, N, hist2, NBLK, bufA, Etot);
  rs_lvl2   <<<NG,256,0,stream>>>(bufA, hist2, NBLK, srcs, off, N, Etot);

  // Layer 1
  k_gemm<128,64><<<gT,256,0,stream>>>(x, W1, 64, 0, hbuf, N);
  k_al<<<(N*8+255)/256,256,0,stream>>>(hbuf, as1, ad1, al_s, al_d, N*8);
  k_agg64<<<gA64,256,0,stream>>>(hbuf, al_s, al_d, off, srcs, b1, featA, N, 1);

  // Layer 2
  k_gemm<64,64><<<gT,256,0,stream>>>(featA, W2, 64, 0, hbuf, N);
  k_al<<<(N*8+255)/256,256,0,stream>>>(hbuf, as2, ad2, al_s, al_d, N*8);
  k_agg64<<<gA64,256,0,stream>>>(hbuf, al_s, al_d, off, srcs, b2, featB, N, 1);

  // Layer 3
  k_gemm<64,64><<<gT,256,0,stream>>>(featB, W3, 64, 0, hbuf, N);
  k_al<<<(N*8+255)/256,256,0,stream>>>(hbuf, as3, ad3, al_s, al_d, N*8);
  k_agg64<<<gA64,256,0,stream>>>(hbuf, al_s, al_d, off, srcs, b3, featA, N, 1);

  // Layer 4
  k_gemm<64,64><<<gT,256,0,stream>>>(featA, W4, 64, 0, hbuf, N);
  k_al<<<(N*8+255)/256,256,0,stream>>>(hbuf, as4, ad4, al_s, al_d, N*8);
  k_agg64<<<gA64,256,0,stream>>>(hbuf, al_s, al_d, off, srcs, b4, featB, N, 1);

  // Layer 5: folded attn logits; chunked aggregate->z then tiled GEMM z@Wf
  k_ws  <<<1,512,0,stream>>>(W5, as5, ad5, wsb, wdb);
  k_wf  <<<(512*40+255)/256,256,0,stream>>>(W5, Wf);
  k_al5b<<<(N*8+255)/256,256,0,stream>>>(featB, wsb, wdb, al_s, al_d, N*8);
  const int CH = 25000;
  for (int base = 0; base < N; base += CH){
    int cnt = (N - base < CH) ? (N - base) : CH;
    k_agg5z<<<(cnt+3)/4,256,0,stream>>>(featB, al_s, al_d, off, srcs, zbuf, base, cnt);
    k_gemm<512,40><<<(cnt+63)/64,256,0,stream>>>(zbuf, Wf, 40, 0, out5 + (size_t)base*40, cnt);
  }

  // mean + bias + log_softmax
  k_final<<<gA,256,0,stream>>>(out5, b5, (float*)d_out, N);
}

// Round 6
// 770.659 us; speedup vs baseline: 5.5583x; 1.2380x over previous
//
#include <hip/hip_runtime.h>
#include <cstddef>
#include <cstdint>

static __device__ __forceinline__ float leaky(float x){ return x >= 0.f ? x : 0.2f*x; }
// bf16 helpers: ushort->float, float->ushort (RNE), pack pair into uint
static __device__ __forceinline__ float bfl(unsigned short v){ return __uint_as_float(((unsigned)v)<<16); }
static __device__ __forceinline__ float blo(unsigned u){ return __uint_as_float(u<<16); }
static __device__ __forceinline__ float bhi(unsigned u){ return __uint_as_float(u & 0xffff0000u); }
static __device__ __forceinline__ unsigned bf16r(float f){
  unsigned u = __float_as_uint(f);
  return (u + 0x7fffu + ((u>>16)&1u)) >> 16;
}
static __device__ __forceinline__ unsigned pk(float lo, float hi){
  return bf16r(lo) | (bf16r(hi)<<16);
}

// ---------------- CSR build: atomic-free MSD bucket sort ----------------
__global__ __launch_bounds__(256) void rs_hist1(const int* __restrict__ edst, int E, int N,
                                                int* __restrict__ hist, int NBLK, int Etot){
  __shared__ int lh[512];
  int t = threadIdx.x, b = blockIdx.x;
  lh[t] = 0; lh[t+256] = 0;
  __syncthreads();
  int base = b*8192;
  for (int i = 0; i < 32; i++){
    int e = base + t + i*256;
    if (e < Etot){
      int d = (e < E) ? edst[e] : (e - E);
      atomicAdd(&lh[d>>8], 1);
    }
  }
  __syncthreads();
  hist[(size_t)t*NBLK + b] = lh[t];
  hist[(size_t)(t+256)*NBLK + b] = lh[t+256];
}
__global__ __launch_bounds__(256) void s_bsum(const int* __restrict__ a, int* __restrict__ bsum, int L){
  __shared__ int sm[256];
  int t = threadIdx.x; int i = blockIdx.x*256 + t;
  sm[t] = (i < L) ? a[i] : 0;
  __syncthreads();
  #pragma unroll
  for (int o=128;o;o>>=1){ if (t<o) sm[t]+=sm[t+o]; __syncthreads(); }
  if (t==0) bsum[blockIdx.x] = sm[0];
}
__global__ __launch_bounds__(512) void k_bscan(const int* __restrict__ bsum, int* __restrict__ boff, int NB){
  __shared__ int sm[512];
  int t = threadIdx.x;
  int v = (t < NB) ? bsum[t] : 0;
  sm[t] = v; __syncthreads();
  for (int o=1;o<512;o<<=1){
    int u = (t>=o) ? sm[t-o] : 0;
    __syncthreads();
    sm[t] += u;
    __syncthreads();
  }
  if (t < NB) boff[t] = sm[t] - v;
  if (t == NB-1) boff[NB] = sm[t];
}
__global__ __launch_bounds__(256) void s_apply(const int* __restrict__ a, const int* __restrict__ boff,
                                               int* __restrict__ out, int L){
  __shared__ int sm[256];
  int t = threadIdx.x, b = blockIdx.x;
  int i = b*256 + t;
  int v = (i < L) ? a[i] : 0;
  sm[t] = v; __syncthreads();
  for (int o=1;o<256;o<<=1){
    int u = (t>=o) ? sm[t-o] : 0;
    __syncthreads();
    sm[t] += u;
    __syncthreads();
  }
  if (i < L) out[i] = boff[b] + sm[t] - v;
}
__global__ __launch_bounds__(256) void rs_scatter1(const int* __restrict__ esrc, const int* __restrict__ edst,
                                                   int E, int N, const int* __restrict__ hist2, int NBLK,
                                                   int2* __restrict__ bufA, int Etot){
  __shared__ int gb[512];
  __shared__ int lcnt[512];
  int t = threadIdx.x, b = blockIdx.x;
  gb[t]     = hist2[(size_t)t*NBLK + b];
  gb[t+256] = hist2[(size_t)(t+256)*NBLK + b];
  lcnt[t] = 0; lcnt[t+256] = 0;
  __syncthreads();
  int base = b*8192;
  for (int i = 0; i < 32; i++){
    int e = base + t + i*256;
    if (e < Etot){
      int s, d;
      if (e < E){ s = esrc[e]; d = edst[e]; }
      else { s = e - E; d = s; }
      int bin = d >> 8;
      int r = atomicAdd(&lcnt[bin], 1);
      bufA[gb[bin] + r] = make_int2(s, d);
    }
  }
}
__global__ __launch_bounds__(256) void rs_lvl2(const int2* __restrict__ bufA, const int* __restrict__ hist2,
                                               int NBLK, int* __restrict__ srcs, int* __restrict__ off,
                                               int N, int Etot){
  __shared__ int cnt[256];
  __shared__ int basev[256];
  int t = threadIdx.x, g = blockIdx.x;
  int beg = hist2[(size_t)g*NBLK];
  int end = (g < 511) ? hist2[(size_t)(g+1)*NBLK] : Etot;
  cnt[t] = 0;
  __syncthreads();
  for (int j = beg + t; j < end; j += 256)
    atomicAdd(&cnt[bufA[j].y & 255], 1);
  __syncthreads();
  int v = cnt[t];
  for (int o=1;o<256;o<<=1){
    int u = (t>=o) ? cnt[t-o] : 0;
    __syncthreads();
    cnt[t] += u;
    __syncthreads();
  }
  basev[t] = cnt[t] - v;
  __syncthreads();
  cnt[t] = 0;
  __syncthreads();
  for (int j = beg + t; j < end; j += 256){
    int2 p = bufA[j];
    int lb = p.y & 255;
    int r = atomicAdd(&cnt[lb], 1);
    srcs[beg + basev[lb] + r] = p.x;
  }
  int node = g*256 + t;
  if (node < N) off[node] = beg + basev[t];
  if (g == 0 && t == 0) off[N] = Etot;
}

// ---------------- GEMM: out[n, m] = A[n,:] @ W[:, col0+m]; OB => bf16 output ----------------
template<int K, int M, bool OB>
__global__ __launch_bounds__(256) void k_gemm(
    const float* __restrict__ A, const float* __restrict__ W, int ldw, int col0,
    void* __restrict__ out, int N)
{
  constexpr int KT = 64;
  constexpr int TX = M/4;
  __shared__ float As[64][KT+1];
  __shared__ alignas(16) float Ws[KT][M];
  int t = threadIdx.x;
  int base = blockIdx.x*64;
  int tx = t % TX, ty = t / TX;
  bool act = ty < 16;
  int n0 = ty*4, m0 = tx*4;
  float acc[4][4] = {};
  for (int kt=0; kt<K; kt+=KT){
    for (int i=t; i<64*(KT/4); i+=256){
      int n  = i >> 4;
      int kq = i & 15;
      float4 v = make_float4(0.f,0.f,0.f,0.f);
      int gn = base + n;
      if (gn < N) v = *(const float4*)(A + (size_t)gn*K + kt + kq*4);
      As[n][kq*4+0]=v.x; As[n][kq*4+1]=v.y; As[n][kq*4+2]=v.z; As[n][kq*4+3]=v.w;
    }
    for (int i=t; i<KT*(M/4); i+=256){
      int k = i/(M/4), mq = i%(M/4);
      *(float4*)&Ws[k][mq*4] = *(const float4*)(W + (size_t)(kt+k)*ldw + col0 + mq*4);
    }
    __syncthreads();
    if (act){
      #pragma unroll 8
      for (int k=0;k<KT;k++){
        float4 w = *(const float4*)&Ws[k][m0];
        float av0 = As[n0+0][k], av1 = As[n0+1][k], av2 = As[n0+2][k], av3 = As[n0+3][k];
        acc[0][0]=fmaf(av0,w.x,acc[0][0]); acc[0][1]=fmaf(av0,w.y,acc[0][1]);
        acc[0][2]=fmaf(av0,w.z,acc[0][2]); acc[0][3]=fmaf(av0,w.w,acc[0][3]);
        acc[1][0]=fmaf(av1,w.x,acc[1][0]); acc[1][1]=fmaf(av1,w.y,acc[1][1]);
        acc[1][2]=fmaf(av1,w.z,acc[1][2]); acc[1][3]=fmaf(av1,w.w,acc[1][3]);
        acc[2][0]=fmaf(av2,w.x,acc[2][0]); acc[2][1]=fmaf(av2,w.y,acc[2][1]);
        acc[2][2]=fmaf(av2,w.z,acc[2][2]); acc[2][3]=fmaf(av2,w.w,acc[2][3]);
        acc[3][0]=fmaf(av3,w.x,acc[3][0]); acc[3][1]=fmaf(av3,w.y,acc[3][1]);
        acc[3][2]=fmaf(av3,w.z,acc[3][2]); acc[3][3]=fmaf(av3,w.w,acc[3][3]);
      }
    }
    __syncthreads();
  }
  if (act){
    #pragma unroll
    for (int i=0;i<4;i++){
      int gn = base + n0 + i;
      if (gn < N){
        if (OB){
          unsigned p0 = pk(acc[i][0], acc[i][1]);
          unsigned p1 = pk(acc[i][2], acc[i][3]);
          *(uint2*)((unsigned short*)out + (size_t)gn*M + m0) = make_uint2(p0, p1);
        } else {
          float4 v = make_float4(acc[i][0],acc[i][1],acc[i][2],acc[i][3]);
          *(float4*)((float*)out + (size_t)gn*M + m0) = v;
        }
      }
    }
  }
}

// ---------------- attention logits (layers 1-4): h bf16 in, al_s bf16 out ----------------
__global__ void k_al(const unsigned short* __restrict__ h16, const float* __restrict__ a_s,
                     const float* __restrict__ a_d, unsigned short* __restrict__ al_s16,
                     float* __restrict__ al_d, int total /* N*8 */)
{
  int idx = blockIdx.x*256 + threadIdx.x;
  if (idx >= total) return;
  int hd = idx & 7;
  uint4 q = *(const uint4*)(h16 + (size_t)idx*8);
  const float4* sp = (const float4*)(a_s + hd*8);
  const float4* dp = (const float4*)(a_d + hd*8);
  float4 s0 = sp[0], s1 = sp[1], d0 = dp[0], d1 = dp[1];
  float f0=blo(q.x), f1=bhi(q.x), f2=blo(q.y), f3=bhi(q.y);
  float f4=blo(q.z), f5=bhi(q.z), f6=blo(q.w), f7=bhi(q.w);
  float s = f0*s0.x + f1*s0.y + f2*s0.z + f3*s0.w
          + f4*s1.x + f5*s1.y + f6*s1.z + f7*s1.w;
  float d = f0*d0.x + f1*d0.y + f2*d0.z + f3*d0.w
          + f4*d1.x + f5*d1.y + f6*d1.z + f7*d1.w;
  al_s16[idx] = (unsigned short)bf16r(s);
  al_d[idx] = d;
}

// ---------------- aggregation (layers 1-4): bf16 gather; OB => bf16 out ----------------
template<bool OB>
__global__ __launch_bounds__(256) void k_agg64(
    const unsigned short* __restrict__ h16, const unsigned short* __restrict__ al16,
    const float* __restrict__ al_d, const int* __restrict__ off,
    const int* __restrict__ srcs, const float* __restrict__ bias,
    void* __restrict__ outf, int N, int apply_act)
{
  int t = threadIdx.x;
  int grp = t >> 3;
  int sub = t & 7;
  int node = blockIdx.x*32 + grp;
  if (node >= N) return;
  int beg = off[node], end = off[node+1];
  float ald = al_d[(size_t)node*8 + sub];
  float s = 0.f;
  float acc[8] = {0.f,0.f,0.f,0.f,0.f,0.f,0.f,0.f};
  int j = beg;
  for (; j+3 < end; j += 4){
    int s0 = srcs[j], s1 = srcs[j+1], s2 = srcs[j+2], s3 = srcs[j+3];
    float e0 = leaky(bfl(al16[(size_t)s0*8 + sub]) + ald);
    float e1 = leaky(bfl(al16[(size_t)s1*8 + sub]) + ald);
    float e2 = leaky(bfl(al16[(size_t)s2*8 + sub]) + ald);
    float e3 = leaky(bfl(al16[(size_t)s3*8 + sub]) + ald);
    float a0 = __expf(e0), a1 = __expf(e1), a2 = __expf(e2), a3 = __expf(e3);
    uint4 q0 = *(const uint4*)(h16 + (size_t)s0*64 + sub*8);
    uint4 q1 = *(const uint4*)(h16 + (size_t)s1*64 + sub*8);
    uint4 q2 = *(const uint4*)(h16 + (size_t)s2*64 + sub*8);
    uint4 q3 = *(const uint4*)(h16 + (size_t)s3*64 + sub*8);
    s += a0 + a1 + a2 + a3;
    acc[0]=fmaf(a0,blo(q0.x),acc[0]); acc[1]=fmaf(a0,bhi(q0.x),acc[1]);
    acc[2]=fmaf(a0,blo(q0.y),acc[2]); acc[3]=fmaf(a0,bhi(q0.y),acc[3]);
    acc[4]=fmaf(a0,blo(q0.z),acc[4]); acc[5]=fmaf(a0,bhi(q0.z),acc[5]);
    acc[6]=fmaf(a0,blo(q0.w),acc[6]); acc[7]=fmaf(a0,bhi(q0.w),acc[7]);
    acc[0]=fmaf(a1,blo(q1.x),acc[0]); acc[1]=fmaf(a1,bhi(q1.x),acc[1]);
    acc[2]=fmaf(a1,blo(q1.y),acc[2]); acc[3]=fmaf(a1,bhi(q1.y),acc[3]);
    acc[4]=fmaf(a1,blo(q1.z),acc[4]); acc[5]=fmaf(a1,bhi(q1.z),acc[5]);
    acc[6]=fmaf(a1,blo(q1.w),acc[6]); acc[7]=fmaf(a1,bhi(q1.w),acc[7]);
    acc[0]=fmaf(a2,blo(q2.x),acc[0]); acc[1]=fmaf(a2,bhi(q2.x),acc[1]);
    acc[2]=fmaf(a2,blo(q2.y),acc[2]); acc[3]=fmaf(a2,bhi(q2.y),acc[3]);
    acc[4]=fmaf(a2,blo(q2.z),acc[4]); acc[5]=fmaf(a2,bhi(q2.z),acc[5]);
    acc[6]=fmaf(a2,blo(q2.w),acc[6]); acc[7]=fmaf(a2,bhi(q2.w),acc[7]);
    acc[0]=fmaf(a3,blo(q3.x),acc[0]); acc[1]=fmaf(a3,bhi(q3.x),acc[1]);
    acc[2]=fmaf(a3,blo(q3.y),acc[2]); acc[3]=fmaf(a3,bhi(q3.y),acc[3]);
    acc[4]=fmaf(a3,blo(q3.z),acc[4]); acc[5]=fmaf(a3,bhi(q3.z),acc[5]);
    acc[6]=fmaf(a3,blo(q3.w),acc[6]); acc[7]=fmaf(a3,bhi(q3.w),acc[7]);
  }
  for (; j < end; ++j){
    int s0 = srcs[j];
    float e0 = leaky(bfl(al16[(size_t)s0*8 + sub]) + ald);
    float a0 = __expf(e0);
    uint4 q0 = *(const uint4*)(h16 + (size_t)s0*64 + sub*8);
    s += a0;
    acc[0]=fmaf(a0,blo(q0.x),acc[0]); acc[1]=fmaf(a0,bhi(q0.x),acc[1]);
    acc[2]=fmaf(a0,blo(q0.y),acc[2]); acc[3]=fmaf(a0,bhi(q0.y),acc[3]);
    acc[4]=fmaf(a0,blo(q0.z),acc[4]); acc[5]=fmaf(a0,bhi(q0.z),acc[5]);
    acc[6]=fmaf(a0,blo(q0.w),acc[6]); acc[7]=fmaf(a0,bhi(q0.w),acc[7]);
  }
  float inv = 1.f/(s + 1e-16f);
  const float4* bp = (const float4*)(bias + sub*8);
  float4 b0 = bp[0], b1 = bp[1];
  float r0 = acc[0]*inv + b0.x, r1 = acc[1]*inv + b0.y;
  float r2 = acc[2]*inv + b0.z, r3 = acc[3]*inv + b0.w;
  float r4 = acc[4]*inv + b1.x, r5 = acc[5]*inv + b1.y;
  float r6 = acc[6]*inv + b1.z, r7 = acc[7]*inv + b1.w;
  if (apply_act){
    r0=leaky(r0); r1=leaky(r1); r2=leaky(r2); r3=leaky(r3);
    r4=leaky(r4); r5=leaky(r5); r6=leaky(r6); r7=leaky(r7);
  }
  if (OB){
    uint4 o;
    o.x = pk(r0,r1); o.y = pk(r2,r3); o.z = pk(r4,r5); o.w = pk(r6,r7);
    *(uint4*)((unsigned short*)outf + (size_t)node*64 + sub*8) = o;
  } else {
    float* op = (float*)outf + (size_t)node*64 + sub*8;
    *(float4*)op = make_float4(r0,r1,r2,r3);
    *(float4*)(op+4) = make_float4(r4,r5,r6,r7);
  }
}

// ---------------- layer 5: folded attention vectors ----------------
__global__ __launch_bounds__(512) void k_ws(const float* __restrict__ W5,
                                            const float* __restrict__ as5,
                                            const float* __restrict__ ad5,
                                            float* __restrict__ ws, float* __restrict__ wd){
  int t = threadIdx.x;
  int h = t >> 6, k = t & 63;
  float s = 0.f, d = 0.f;
  #pragma unroll 8
  for (int c=0;c<40;c++){
    float w = W5[(size_t)k*320 + h*40 + c];
    s = fmaf(w, as5[h*40+c], s);
    d = fmaf(w, ad5[h*40+c], d);
  }
  ws[h*64+k] = s; wd[h*64+k] = d;
}
__global__ void k_wf(const float* __restrict__ W5, float* __restrict__ Wf){
  int i = blockIdx.x*256 + threadIdx.x;
  if (i >= 512*40) return;
  int row = i / 40, c = i - row*40;
  int h = row >> 6, k = row & 63;
  Wf[i] = W5[(size_t)k*320 + h*40 + c];
}
__global__ void k_al5b(const unsigned short* __restrict__ f16, const float* __restrict__ ws,
                       const float* __restrict__ wd, unsigned short* __restrict__ al_s16,
                       float* __restrict__ al_d, int total /* N*8 */)
{
  int idx = blockIdx.x*256 + threadIdx.x;
  if (idx >= total) return;
  int n = idx >> 3, h = idx & 7;
  const uint4* fp = (const uint4*)(f16 + (size_t)n*64);
  const float4* ap = (const float4*)(ws + h*64);
  const float4* bp = (const float4*)(wd + h*64);
  float s = 0.f, d = 0.f;
  #pragma unroll
  for (int q=0;q<8;q++){
    uint4 f = fp[q];
    float4 a0 = ap[q*2], a1 = ap[q*2+1];
    float4 b0 = bp[q*2], b1 = bp[q*2+1];
    float f0=blo(f.x), f1=bhi(f.x), f2=blo(f.y), f3=bhi(f.y);
    float f4=blo(f.z), f5=bhi(f.z), f6=blo(f.w), f7=bhi(f.w);
    s += f0*a0.x + f1*a0.y + f2*a0.z + f3*a0.w + f4*a1.x + f5*a1.y + f6*a1.z + f7*a1.w;
    d += f0*b0.x + f1*b0.y + f2*b0.z + f3*b0.w + f4*b1.x + f5*b1.y + f6*b1.z + f7*b1.w;
  }
  al_s16[idx] = (unsigned short)bf16r(s);
  al_d[idx] = d;
}

// ---------------- layer 5 aggregation in input space -> z[local_n][h*64+k] ----------------
__global__ __launch_bounds__(256) void k_agg5z(
    const unsigned short* __restrict__ f16, const unsigned short* __restrict__ al16,
    const float* __restrict__ al_d, const int* __restrict__ off,
    const int* __restrict__ srcs, float* __restrict__ z, int base, int cnt)
{
  int t = threadIdx.x;
  int w = t >> 6;
  int ln = blockIdx.x*4 + w;
  if (ln >= cnt) return;
  int node = base + ln;
  int tl = t & 63;
  int hd = tl & 7;
  int cb = tl >> 3;
  int beg = off[node], end = off[node+1];
  float ald = al_d[(size_t)node*8 + hd];
  int lanebase = hd*4;
  int cbo = cb*8;
  float s = 0.f;
  float acc[8] = {0.f,0.f,0.f,0.f,0.f,0.f,0.f,0.f};
  for (int jb = beg; jb < end; jb += 8){
    int j = jb + cb;
    float atil = 0.f; int si = 0;
    if (j < end){
      si = srcs[j];
      atil = __expf(leaky(bfl(al16[(size_t)si*8 + hd]) + ald));
    }
    s += atil;
    #pragma unroll 8
    for (int e = 0; e < 8; e++){
      if (jb + e >= end) break;
      float ae = __uint_as_float(__builtin_amdgcn_ds_bpermute(lanebase + e*32, __float_as_uint(atil)));
      int sie = __builtin_amdgcn_readlane(si, e*8);
      uint4 q = *(const uint4*)(f16 + (size_t)sie*64 + cbo);
      acc[0]=fmaf(ae,blo(q.x),acc[0]); acc[1]=fmaf(ae,bhi(q.x),acc[1]);
      acc[2]=fmaf(ae,blo(q.y),acc[2]); acc[3]=fmaf(ae,bhi(q.y),acc[3]);
      acc[4]=fmaf(ae,blo(q.z),acc[4]); acc[5]=fmaf(ae,bhi(q.z),acc[5]);
      acc[6]=fmaf(ae,blo(q.w),acc[6]); acc[7]=fmaf(ae,bhi(q.w),acc[7]);
    }
  }
  s += __shfl_xor(s, 8, 64);
  s += __shfl_xor(s, 16, 64);
  s += __shfl_xor(s, 32, 64);
  float inv = 1.f/(s + 1e-16f);
  float4 o0 = make_float4(acc[0]*inv, acc[1]*inv, acc[2]*inv, acc[3]*inv);
  float4 o1 = make_float4(acc[4]*inv, acc[5]*inv, acc[6]*inv, acc[7]*inv);
  float* zp = z + (size_t)ln*512 + hd*64 + cbo;
  *(float4*)zp = o0; *(float4*)(zp+4) = o1;
}

// ---------------- final: mean over heads + bias + log_softmax ----------------
__global__ __launch_bounds__(256) void k_final(
    const float* __restrict__ acc, const float* __restrict__ b5,
    float* __restrict__ out, int N)
{
  int t = threadIdx.x;
  int node = blockIdx.x*4 + (t >> 6);
  if (node >= N) return;
  int tl = t & 63;
  float v = (tl < 40) ? acc[(size_t)node*40 + tl]*0.125f + b5[tl] : -1e30f;
  float m = v;
  #pragma unroll
  for (int o=32;o;o>>=1) m = fmaxf(m, __shfl_xor(m, o, 64));
  float ex = (tl < 40) ? __expf(v - m) : 0.f;
  float s = ex;
  #pragma unroll
  for (int o=32;o;o>>=1) s += __shfl_xor(s, o, 64);
  if (tl < 40) out[(size_t)node*40 + tl] = (v - m) - __logf(s);
}

extern "C" void kernel_launch(void* const* d_in, const int* in_sizes, int n_in,
                              void* d_out, int out_size, void* d_ws, size_t ws_size,
                              hipStream_t stream) {
  const float* x  = (const float*)d_in[0];
  const int*   ei = (const int*)d_in[1];
  const int N = in_sizes[0] / 128;
  const int E = in_sizes[1] / 2;
  const int* esrc = ei;
  const int* edst = ei + E;
  const float* W1 = (const float*)d_in[2];
  const float* as1= (const float*)d_in[3];
  const float* ad1= (const float*)d_in[4];
  const float* b1 = (const float*)d_in[5];
  const float* W2 = (const float*)d_in[6];
  const float* as2= (const float*)d_in[7];
  const float* ad2= (const float*)d_in[8];
  const float* b2 = (const float*)d_in[9];
  const float* W3 = (const float*)d_in[10];
  const float* as3= (const float*)d_in[11];
  const float* ad3= (const float*)d_in[12];
  const float* b3 = (const float*)d_in[13];
  const float* W4 = (const float*)d_in[14];
  const float* as4= (const float*)d_in[15];
  const float* ad4= (const float*)d_in[16];
  const float* b4 = (const float*)d_in[17];
  const float* W5 = (const float*)d_in[18];
  const float* as5= (const float*)d_in[19];
  const float* ad5= (const float*)d_in[20];
  const float* b5 = (const float*)d_in[21];

  char* p = (char*)d_ws;
  auto alloc = [&](size_t bytes)->void*{
    uintptr_t u = (uintptr_t)p;
    u = (u + 255) & ~(uintptr_t)255;
    void* r = (void*)u;
    p = (char*)u + bytes;
    return r;
  };
  const int Etot = E + N;
  const int NBLK = (Etot + 8191)/8192;
  const int L    = 512*NBLK;
  const int NB2  = (L + 255)/256;
  const int NG   = (N + 255)/256;

  int* off    = (int*)alloc((size_t)(N+1)*4);
  int* srcs   = (int*)alloc((size_t)Etot*4);
  int* hist   = (int*)alloc((size_t)L*4);
  int* hist2  = (int*)alloc((size_t)L*4);
  int* hb     = (int*)alloc((size_t)(NB2+1)*4);
  unsigned short* al_s16 = (unsigned short*)alloc((size_t)N*8*2);
  float* al_d = (float*)alloc((size_t)N*8*4);
  unsigned short* h16  = (unsigned short*)alloc((size_t)N*64*2);
  unsigned short* fB16 = (unsigned short*)alloc((size_t)N*64*2);
  float* featA= (float*)alloc((size_t)N*64*4);   // featA+featB contiguous -> z overlay
  float* featB= (float*)alloc((size_t)N*64*4);
  float* wsb  = (float*)alloc((size_t)8*64*4);
  float* wdb  = (float*)alloc((size_t)8*64*4);
  float* Wf   = (float*)alloc((size_t)512*40*4);
  float* out5 = (float*)alloc((size_t)N*40*4);
  float* zbuf = featA;                           // 2*N*64*4 = 51.2MB >= 25000*512*4
  int2* bufA  = (int2*)featA;                    // sort scratch (dead before features)

  int gT = (N+63)/64, gA = (N+3)/4;
  int gA64 = (N+31)/32;
  int gAl = (N*8+255)/256;

  // CSR: atomic-free two-level bucket sort (self-loops synthesized)
  rs_hist1  <<<NBLK,256,0,stream>>>(edst, E, N, hist, NBLK, Etot);
  s_bsum    <<<NB2,256,0,stream>>>(hist, hb, L);
  k_bscan   <<<1,512,0,stream>>>(hb, hb, NB2);
  s_apply   <<<NB2,256,0,stream>>>(hist, hb, hist2, L);
  rs_scatter1<<<NBLK,256,0,stream>>>(esrc, edst, E, N, hist2, NBLK, bufA, Etot);
  rs_lvl2   <<<NG,256,0,stream>>>(bufA, hist2, NBLK, srcs, off, N, Etot);

  // Layer 1
  k_gemm<128,64,true><<<gT,256,0,stream>>>(x, W1, 64, 0, h16, N);
  k_al<<<gAl,256,0,stream>>>(h16, as1, ad1, al_s16, al_d, N*8);
  k_agg64<false><<<gA64,256,0,stream>>>(h16, al_s16, al_d, off, srcs, b1, featA, N, 1);

  // Layer 2
  k_gemm<64,64,true><<<gT,256,0,stream>>>(featA, W2, 64, 0, h16, N);
  k_al<<<gAl,256,0,stream>>>(h16, as2, ad2, al_s16, al_d, N*8);
  k_agg64<false><<<gA64,256,0,stream>>>(h16, al_s16, al_d, off, srcs, b2, featB, N, 1);

  // Layer 3
  k_gemm<64,64,true><<<gT,256,0,stream>>>(featB, W3, 64, 0, h16, N);
  k_al<<<gAl,256,0,stream>>>(h16, as3, ad3, al_s16, al_d, N*8);
  k_agg64<false><<<gA64,256,0,stream>>>(h16, al_s16, al_d, off, srcs, b3, featA, N, 1);

  // Layer 4 -> bf16 output (gathered by layer 5)
  k_gemm<64,64,true><<<gT,256,0,stream>>>(featA, W4, 64, 0, h16, N);
  k_al<<<gAl,256,0,stream>>>(h16, as4, ad4, al_s16, al_d, N*8);
  k_agg64<true><<<gA64,256,0,stream>>>(h16, al_s16, al_d, off, srcs, b4, fB16, N, 1);

  // Layer 5: folded attn logits; chunked aggregate->z then tiled GEMM z@Wf
  k_ws  <<<1,512,0,stream>>>(W5, as5, ad5, wsb, wdb);
  k_wf  <<<(512*40+255)/256,256,0,stream>>>(W5, Wf);
  k_al5b<<<gAl,256,0,stream>>>(fB16, wsb, wdb, al_s16, al_d, N*8);
  const int CH = 25000;
  for (int base = 0; base < N; base += CH){
    int cnt = (N - base < CH) ? (N - base) : CH;
    k_agg5z<<<(cnt+3)/4,256,0,stream>>>(fB16, al_s16, al_d, off, srcs, zbuf, base, cnt);
    k_gemm<512,40,false><<<(cnt+63)/64,256,0,stream>>>(zbuf, Wf, 40, 0, out5 + (size_t)base*40, cnt);
  }

  // mean + bias + log_softmax
  k_final<<<gA,256,0,stream>>>(out5, b5, (float*)d_out, N);
}

// Round 7
// 653.331 us; speedup vs baseline: 6.5565x; 1.1796x over previous
//
#include <hip/hip_runtime.h>
#include <cstddef>
#include <cstdint>

static __device__ __forceinline__ float leaky(float x){ return x >= 0.f ? x : 0.2f*x; }
// bf16 helpers
static __device__ __forceinline__ float bfl(unsigned short v){ return __uint_as_float(((unsigned)v)<<16); }
static __device__ __forceinline__ float blo(unsigned u){ return __uint_as_float(u<<16); }
static __device__ __forceinline__ float bhi(unsigned u){ return __uint_as_float(u & 0xffff0000u); }
static __device__ __forceinline__ unsigned bf16r(float f){
  unsigned u = __float_as_uint(f);
  return (u + 0x7fffu + ((u>>16)&1u)) >> 16;
}
static __device__ __forceinline__ unsigned pk(float lo, float hi){
  return bf16r(lo) | (bf16r(hi)<<16);
}

// ---------------- CSR build: atomic-free MSD bucket sort ----------------
__global__ __launch_bounds__(256) void rs_hist1(const int* __restrict__ edst, int E, int N,
                                                int* __restrict__ hist, int NBLK, int Etot){
  __shared__ int lh[512];
  int t = threadIdx.x, b = blockIdx.x;
  lh[t] = 0; lh[t+256] = 0;
  __syncthreads();
  int base = b*8192;
  for (int i = 0; i < 32; i++){
    int e = base + t + i*256;
    if (e < Etot){
      int d = (e < E) ? edst[e] : (e - E);
      atomicAdd(&lh[d>>8], 1);
    }
  }
  __syncthreads();
  hist[(size_t)t*NBLK + b] = lh[t];
  hist[(size_t)(t+256)*NBLK + b] = lh[t+256];
}
__global__ __launch_bounds__(256) void s_bsum(const int* __restrict__ a, int* __restrict__ bsum, int L){
  __shared__ int sm[256];
  int t = threadIdx.x; int i = blockIdx.x*256 + t;
  sm[t] = (i < L) ? a[i] : 0;
  __syncthreads();
  #pragma unroll
  for (int o=128;o;o>>=1){ if (t<o) sm[t]+=sm[t+o]; __syncthreads(); }
  if (t==0) bsum[blockIdx.x] = sm[0];
}
__global__ __launch_bounds__(512) void k_bscan(const int* __restrict__ bsum, int* __restrict__ boff, int NB){
  __shared__ int sm[512];
  int t = threadIdx.x;
  int v = (t < NB) ? bsum[t] : 0;
  sm[t] = v; __syncthreads();
  for (int o=1;o<512;o<<=1){
    int u = (t>=o) ? sm[t-o] : 0;
    __syncthreads();
    sm[t] += u;
    __syncthreads();
  }
  if (t < NB) boff[t] = sm[t] - v;
  if (t == NB-1) boff[NB] = sm[t];
}
__global__ __launch_bounds__(256) void s_apply(const int* __restrict__ a, const int* __restrict__ boff,
                                               int* __restrict__ out, int L){
  __shared__ int sm[256];
  int t = threadIdx.x, b = blockIdx.x;
  int i = b*256 + t;
  int v = (i < L) ? a[i] : 0;
  sm[t] = v; __syncthreads();
  for (int o=1;o<256;o<<=1){
    int u = (t>=o) ? sm[t-o] : 0;
    __syncthreads();
    sm[t] += u;
    __syncthreads();
  }
  if (i < L) out[i] = boff[b] + sm[t] - v;
}
__global__ __launch_bounds__(256) void rs_scatter1(const int* __restrict__ esrc, const int* __restrict__ edst,
                                                   int E, int N, const int* __restrict__ hist2, int NBLK,
                                                   int2* __restrict__ bufA, int Etot){
  __shared__ int gb[512];
  __shared__ int lcnt[512];
  int t = threadIdx.x, b = blockIdx.x;
  gb[t]     = hist2[(size_t)t*NBLK + b];
  gb[t+256] = hist2[(size_t)(t+256)*NBLK + b];
  lcnt[t] = 0; lcnt[t+256] = 0;
  __syncthreads();
  int base = b*8192;
  for (int i = 0; i < 32; i++){
    int e = base + t + i*256;
    if (e < Etot){
      int s, d;
      if (e < E){ s = esrc[e]; d = edst[e]; }
      else { s = e - E; d = s; }
      int bin = d >> 8;
      int r = atomicAdd(&lcnt[bin], 1);
      bufA[gb[bin] + r] = make_int2(s, d);
    }
  }
}
__global__ __launch_bounds__(256) void rs_lvl2(const int2* __restrict__ bufA, const int* __restrict__ hist2,
                                               int NBLK, int* __restrict__ srcs, int* __restrict__ off,
                                               int N, int Etot){
  __shared__ int cnt[256];
  __shared__ int basev[256];
  int t = threadIdx.x, g = blockIdx.x;
  int beg = hist2[(size_t)g*NBLK];
  int end = (g < 511) ? hist2[(size_t)(g+1)*NBLK] : Etot;
  cnt[t] = 0;
  __syncthreads();
  for (int j = beg + t; j < end; j += 256)
    atomicAdd(&cnt[bufA[j].y & 255], 1);
  __syncthreads();
  int v = cnt[t];
  for (int o=1;o<256;o<<=1){
    int u = (t>=o) ? cnt[t-o] : 0;
    __syncthreads();
    cnt[t] += u;
    __syncthreads();
  }
  basev[t] = cnt[t] - v;
  __syncthreads();
  cnt[t] = 0;
  __syncthreads();
  for (int j = beg + t; j < end; j += 256){
    int2 p = bufA[j];
    int lb = p.y & 255;
    int r = atomicAdd(&cnt[lb], 1);
    srcs[beg + basev[lb] + r] = p.x;
  }
  int node = g*256 + t;
  if (node < N) off[node] = beg + basev[t];
  if (g == 0 && t == 0) off[N] = Etot;
}

// ---------------- GEMM: out[n, m] = A[n,:] @ W[:, col0+m]; OB => bf16 output ----------------
template<int K, int M, bool OB>
__global__ __launch_bounds__(256) void k_gemm(
    const float* __restrict__ A, const float* __restrict__ W, int ldw, int col0,
    void* __restrict__ out, int N)
{
  constexpr int KT = 64;
  constexpr int TX = M/4;
  __shared__ float As[64][KT+1];
  __shared__ alignas(16) float Ws[KT][M];
  int t = threadIdx.x;
  int base = blockIdx.x*64;
  int tx = t % TX, ty = t / TX;
  bool act = ty < 16;
  int n0 = ty*4, m0 = tx*4;
  float acc[4][4] = {};
  for (int kt=0; kt<K; kt+=KT){
    for (int i=t; i<64*(KT/4); i+=256){
      int n  = i >> 4;
      int kq = i & 15;
      float4 v = make_float4(0.f,0.f,0.f,0.f);
      int gn = base + n;
      if (gn < N) v = *(const float4*)(A + (size_t)gn*K + kt + kq*4);
      As[n][kq*4+0]=v.x; As[n][kq*4+1]=v.y; As[n][kq*4+2]=v.z; As[n][kq*4+3]=v.w;
    }
    for (int i=t; i<KT*(M/4); i+=256){
      int k = i/(M/4), mq = i%(M/4);
      *(float4*)&Ws[k][mq*4] = *(const float4*)(W + (size_t)(kt+k)*ldw + col0 + mq*4);
    }
    __syncthreads();
    if (act){
      #pragma unroll 8
      for (int k=0;k<KT;k++){
        float4 w = *(const float4*)&Ws[k][m0];
        float av0 = As[n0+0][k], av1 = As[n0+1][k], av2 = As[n0+2][k], av3 = As[n0+3][k];
        acc[0][0]=fmaf(av0,w.x,acc[0][0]); acc[0][1]=fmaf(av0,w.y,acc[0][1]);
        acc[0][2]=fmaf(av0,w.z,acc[0][2]); acc[0][3]=fmaf(av0,w.w,acc[0][3]);
        acc[1][0]=fmaf(av1,w.x,acc[1][0]); acc[1][1]=fmaf(av1,w.y,acc[1][1]);
        acc[1][2]=fmaf(av1,w.z,acc[1][2]); acc[1][3]=fmaf(av1,w.w,acc[1][3]);
        acc[2][0]=fmaf(av2,w.x,acc[2][0]); acc[2][1]=fmaf(av2,w.y,acc[2][1]);
        acc[2][2]=fmaf(av2,w.z,acc[2][2]); acc[2][3]=fmaf(av2,w.w,acc[2][3]);
        acc[3][0]=fmaf(av3,w.x,acc[3][0]); acc[3][1]=fmaf(av3,w.y,acc[3][1]);
        acc[3][2]=fmaf(av3,w.z,acc[3][2]); acc[3][3]=fmaf(av3,w.w,acc[3][3]);
      }
    }
    __syncthreads();
  }
  if (act){
    #pragma unroll
    for (int i=0;i<4;i++){
      int gn = base + n0 + i;
      if (gn < N){
        if (OB){
          unsigned p0 = pk(acc[i][0], acc[i][1]);
          unsigned p1 = pk(acc[i][2], acc[i][3]);
          *(uint2*)((unsigned short*)out + (size_t)gn*M + m0) = make_uint2(p0, p1);
        } else {
          float4 v = make_float4(acc[i][0],acc[i][1],acc[i][2],acc[i][3]);
          *(float4*)((float*)out + (size_t)gn*M + m0) = v;
        }
      }
    }
  }
}

// ---------------- layer-5 z[bf16, Kz=512] @ Wf[512,40] -> out5 fp32; full 320-thread tile ----------------
__global__ __launch_bounds__(320) void k_gemm5(
    const unsigned short* __restrict__ z16, const float* __restrict__ Wf,
    float* __restrict__ out5, int base, int cnt)
{
  __shared__ float As[64][65];
  __shared__ alignas(16) float Ws[64][40];
  int t = threadIdx.x;
  int rb = blockIdx.x*64;
  int tx = t % 10, ty = t / 10;          // ty 0..31
  int n0 = ty*2, m0 = tx*4;
  float acc[2][4] = {};
  for (int kt = 0; kt < 512; kt += 64){
    for (int i = t; i < 512; i += 320){  // A: 64 rows x 64 k bf16, 8 bf16 per uint4
      int n = i >> 3, kq = i & 7;
      uint4 q = make_uint4(0,0,0,0);
      int ln = rb + n;
      if (ln < cnt) q = *(const uint4*)(z16 + (size_t)ln*512 + kt + kq*8);
      float* ap = &As[n][kq*8];
      ap[0]=blo(q.x); ap[1]=bhi(q.x); ap[2]=blo(q.y); ap[3]=bhi(q.y);
      ap[4]=blo(q.z); ap[5]=bhi(q.z); ap[6]=blo(q.w); ap[7]=bhi(q.w);
    }
    for (int i = t; i < 640; i += 320){  // W: 64 x 40 as float4
      int k = i / 10, mq = i % 10;
      *(float4*)&Ws[k][mq*4] = *(const float4*)(Wf + (size_t)(kt+k)*40 + mq*4);
    }
    __syncthreads();
    #pragma unroll 8
    for (int k=0;k<64;k++){
      float4 w = *(const float4*)&Ws[k][m0];
      float a0 = As[n0][k], a1 = As[n0+1][k];
      acc[0][0]=fmaf(a0,w.x,acc[0][0]); acc[0][1]=fmaf(a0,w.y,acc[0][1]);
      acc[0][2]=fmaf(a0,w.z,acc[0][2]); acc[0][3]=fmaf(a0,w.w,acc[0][3]);
      acc[1][0]=fmaf(a1,w.x,acc[1][0]); acc[1][1]=fmaf(a1,w.y,acc[1][1]);
      acc[1][2]=fmaf(a1,w.z,acc[1][2]); acc[1][3]=fmaf(a1,w.w,acc[1][3]);
    }
    __syncthreads();
  }
  #pragma unroll
  for (int r=0;r<2;r++){
    int ln = rb + n0 + r;
    if (ln < cnt){
      *(float4*)(out5 + (size_t)(base+ln)*40 + m0) =
        make_float4(acc[r][0],acc[r][1],acc[r][2],acc[r][3]);
    }
  }
}

// ---------------- attention logits (layers 1-4): h bf16 in, al_s bf16 out ----------------
__global__ void k_al(const unsigned short* __restrict__ h16, const float* __restrict__ a_s,
                     const float* __restrict__ a_d, unsigned short* __restrict__ al_s16,
                     float* __restrict__ al_d, int total /* N*8 */)
{
  int idx = blockIdx.x*256 + threadIdx.x;
  if (idx >= total) return;
  int hd = idx & 7;
  uint4 q = *(const uint4*)(h16 + (size_t)idx*8);
  const float4* sp = (const float4*)(a_s + hd*8);
  const float4* dp = (const float4*)(a_d + hd*8);
  float4 s0 = sp[0], s1 = sp[1], d0 = dp[0], d1 = dp[1];
  float f0=blo(q.x), f1=bhi(q.x), f2=blo(q.y), f3=bhi(q.y);
  float f4=blo(q.z), f5=bhi(q.z), f6=blo(q.w), f7=bhi(q.w);
  float s = f0*s0.x + f1*s0.y + f2*s0.z + f3*s0.w
          + f4*s1.x + f5*s1.y + f6*s1.z + f7*s1.w;
  float d = f0*d0.x + f1*d0.y + f2*d0.z + f3*d0.w
          + f4*d1.x + f5*d1.y + f6*d1.z + f7*d1.w;
  al_s16[idx] = (unsigned short)bf16r(s);
  al_d[idx] = d;
}

// ---------------- aggregation (layers 1-4): bf16 gather; OB => bf16 out ----------------
template<bool OB>
__global__ __launch_bounds__(256) void k_agg64(
    const unsigned short* __restrict__ h16, const unsigned short* __restrict__ al16,
    const float* __restrict__ al_d, const int* __restrict__ off,
    const int* __restrict__ srcs, const float* __restrict__ bias,
    void* __restrict__ outf, int N, int apply_act)
{
  int t = threadIdx.x;
  int grp = t >> 3;
  int sub = t & 7;
  int node = blockIdx.x*32 + grp;
  if (node >= N) return;
  int beg = off[node], end = off[node+1];
  float ald = al_d[(size_t)node*8 + sub];
  float s = 0.f;
  float acc[8] = {0.f,0.f,0.f,0.f,0.f,0.f,0.f,0.f};
  int j = beg;
  for (; j+3 < end; j += 4){
    int s0 = srcs[j], s1 = srcs[j+1], s2 = srcs[j+2], s3 = srcs[j+3];
    float e0 = leaky(bfl(al16[(size_t)s0*8 + sub]) + ald);
    float e1 = leaky(bfl(al16[(size_t)s1*8 + sub]) + ald);
    float e2 = leaky(bfl(al16[(size_t)s2*8 + sub]) + ald);
    float e3 = leaky(bfl(al16[(size_t)s3*8 + sub]) + ald);
    float a0 = __expf(e0), a1 = __expf(e1), a2 = __expf(e2), a3 = __expf(e3);
    uint4 q0 = *(const uint4*)(h16 + (size_t)s0*64 + sub*8);
    uint4 q1 = *(const uint4*)(h16 + (size_t)s1*64 + sub*8);
    uint4 q2 = *(const uint4*)(h16 + (size_t)s2*64 + sub*8);
    uint4 q3 = *(const uint4*)(h16 + (size_t)s3*64 + sub*8);
    s += a0 + a1 + a2 + a3;
    acc[0]=fmaf(a0,blo(q0.x),acc[0]); acc[1]=fmaf(a0,bhi(q0.x),acc[1]);
    acc[2]=fmaf(a0,blo(q0.y),acc[2]); acc[3]=fmaf(a0,bhi(q0.y),acc[3]);
    acc[4]=fmaf(a0,blo(q0.z),acc[4]); acc[5]=fmaf(a0,bhi(q0.z),acc[5]);
    acc[6]=fmaf(a0,blo(q0.w),acc[6]); acc[7]=fmaf(a0,bhi(q0.w),acc[7]);
    acc[0]=fmaf(a1,blo(q1.x),acc[0]); acc[1]=fmaf(a1,bhi(q1.x),acc[1]);
    acc[2]=fmaf(a1,blo(q1.y),acc[2]); acc[3]=fmaf(a1,bhi(q1.y),acc[3]);
    acc[4]=fmaf(a1,blo(q1.z),acc[4]); acc[5]=fmaf(a1,bhi(q1.z),acc[5]);
    acc[6]=fmaf(a1,blo(q1.w),acc[6]); acc[7]=fmaf(a1,bhi(q1.w),acc[7]);
    acc[0]=fmaf(a2,blo(q2.x),acc[0]); acc[1]=fmaf(a2,bhi(q2.x),acc[1]);
    acc[2]=fmaf(a2,blo(q2.y),acc[2]); acc[3]=fmaf(a2,bhi(q2.y),acc[3]);
    acc[4]=fmaf(a2,blo(q2.z),acc[4]); acc[5]=fmaf(a2,bhi(q2.z),acc[5]);
    acc[6]=fmaf(a2,blo(q2.w),acc[6]); acc[7]=fmaf(a2,bhi(q2.w),acc[7]);
    acc[0]=fmaf(a3,blo(q3.x),acc[0]); acc[1]=fmaf(a3,bhi(q3.x),acc[1]);
    acc[2]=fmaf(a3,blo(q3.y),acc[2]); acc[3]=fmaf(a3,bhi(q3.y),acc[3]);
    acc[4]=fmaf(a3,blo(q3.z),acc[4]); acc[5]=fmaf(a3,bhi(q3.z),acc[5]);
    acc[6]=fmaf(a3,blo(q3.w),acc[6]); acc[7]=fmaf(a3,bhi(q3.w),acc[7]);
  }
  for (; j < end; ++j){
    int s0 = srcs[j];
    float e0 = leaky(bfl(al16[(size_t)s0*8 + sub]) + ald);
    float a0 = __expf(e0);
    uint4 q0 = *(const uint4*)(h16 + (size_t)s0*64 + sub*8);
    s += a0;
    acc[0]=fmaf(a0,blo(q0.x),acc[0]); acc[1]=fmaf(a0,bhi(q0.x),acc[1]);
    acc[2]=fmaf(a0,blo(q0.y),acc[2]); acc[3]=fmaf(a0,bhi(q0.y),acc[3]);
    acc[4]=fmaf(a0,blo(q0.z),acc[4]); acc[5]=fmaf(a0,bhi(q0.z),acc[5]);
    acc[6]=fmaf(a0,blo(q0.w),acc[6]); acc[7]=fmaf(a0,bhi(q0.w),acc[7]);
  }
  float inv = 1.f/(s + 1e-16f);
  const float4* bp = (const float4*)(bias + sub*8);
  float4 b0 = bp[0], b1 = bp[1];
  float r0 = acc[0]*inv + b0.x, r1 = acc[1]*inv + b0.y;
  float r2 = acc[2]*inv + b0.z, r3 = acc[3]*inv + b0.w;
  float r4 = acc[4]*inv + b1.x, r5 = acc[5]*inv + b1.y;
  float r6 = acc[6]*inv + b1.z, r7 = acc[7]*inv + b1.w;
  if (apply_act){
    r0=leaky(r0); r1=leaky(r1); r2=leaky(r2); r3=leaky(r3);
    r4=leaky(r4); r5=leaky(r5); r6=leaky(r6); r7=leaky(r7);
  }
  if (OB){
    uint4 o;
    o.x = pk(r0,r1); o.y = pk(r2,r3); o.z = pk(r4,r5); o.w = pk(r6,r7);
    *(uint4*)((unsigned short*)outf + (size_t)node*64 + sub*8) = o;
  } else {
    float* op = (float*)outf + (size_t)node*64 + sub*8;
    *(float4*)op = make_float4(r0,r1,r2,r3);
    *(float4*)(op+4) = make_float4(r4,r5,r6,r7);
  }
}

// ---------------- layer 5: folded attention vectors ----------------
__global__ __launch_bounds__(512) void k_ws(const float* __restrict__ W5,
                                            const float* __restrict__ as5,
                                            const float* __restrict__ ad5,
                                            float* __restrict__ ws, float* __restrict__ wd){
  int t = threadIdx.x;
  int h = t >> 6, k = t & 63;
  float s = 0.f, d = 0.f;
  #pragma unroll 8
  for (int c=0;c<40;c++){
    float w = W5[(size_t)k*320 + h*40 + c];
    s = fmaf(w, as5[h*40+c], s);
    d = fmaf(w, ad5[h*40+c], d);
  }
  ws[h*64+k] = s; wd[h*64+k] = d;
}
__global__ void k_wf(const float* __restrict__ W5, float* __restrict__ Wf){
  int i = blockIdx.x*256 + threadIdx.x;
  if (i >= 512*40) return;
  int row = i / 40, c = i - row*40;
  int h = row >> 6, k = row & 63;
  Wf[i] = W5[(size_t)k*320 + h*40 + c];
}
__global__ void k_al5b(const unsigned short* __restrict__ f16, const float* __restrict__ ws,
                       const float* __restrict__ wd, unsigned short* __restrict__ al_s16,
                       float* __restrict__ al_d, int total /* N*8 */)
{
  int idx = blockIdx.x*256 + threadIdx.x;
  if (idx >= total) return;
  int n = idx >> 3, h = idx & 7;
  const uint4* fp = (const uint4*)(f16 + (size_t)n*64);
  const float4* ap = (const float4*)(ws + h*64);
  const float4* bp = (const float4*)(wd + h*64);
  float s = 0.f, d = 0.f;
  #pragma unroll
  for (int q=0;q<8;q++){
    uint4 f = fp[q];
    float4 a0 = ap[q*2], a1 = ap[q*2+1];
    float4 b0 = bp[q*2], b1 = bp[q*2+1];
    float f0=blo(f.x), f1=bhi(f.x), f2=blo(f.y), f3=bhi(f.y);
    float f4=blo(f.z), f5=bhi(f.z), f6=blo(f.w), f7=bhi(f.w);
    s += f0*a0.x + f1*a0.y + f2*a0.z + f3*a0.w + f4*a1.x + f5*a1.y + f6*a1.z + f7*a1.w;
    d += f0*b0.x + f1*b0.y + f2*b0.z + f3*b0.w + f4*b1.x + f5*b1.y + f6*b1.z + f7*b1.w;
  }
  al_s16[idx] = (unsigned short)bf16r(s);
  al_d[idx] = d;
}

// ---------------- layer 5 aggregation in input space -> z16[local_n][h*64+k] (bf16) ----------------
__global__ __launch_bounds__(256) void k_agg5z(
    const unsigned short* __restrict__ f16, const unsigned short* __restrict__ al16,
    const float* __restrict__ al_d, const int* __restrict__ off,
    const int* __restrict__ srcs, unsigned short* __restrict__ z16, int base, int cnt)
{
  int t = threadIdx.x;
  int w = t >> 6;
  int ln = blockIdx.x*4 + w;
  if (ln >= cnt) return;
  int node = base + ln;
  int tl = t & 63;
  int hd = tl & 7;
  int cb = tl >> 3;
  int beg = off[node], end = off[node+1];
  float ald = al_d[(size_t)node*8 + hd];
  int lanebase = hd*4;
  int cbo = cb*8;
  float s = 0.f;
  float acc[8] = {0.f,0.f,0.f,0.f,0.f,0.f,0.f,0.f};
  for (int jb = beg; jb < end; jb += 8){
    int j = jb + cb;
    float atil = 0.f; int si = 0;
    if (j < end){
      si = srcs[j];
      atil = __expf(leaky(bfl(al16[(size_t)si*8 + hd]) + ald));
    }
    s += atil;
    #pragma unroll 8
    for (int e = 0; e < 8; e++){
      if (jb + e >= end) break;
      float ae = __uint_as_float(__builtin_amdgcn_ds_bpermute(lanebase + e*32, __float_as_uint(atil)));
      int sie = __builtin_amdgcn_readlane(si, e*8);
      uint4 q = *(const uint4*)(f16 + (size_t)sie*64 + cbo);
      acc[0]=fmaf(ae,blo(q.x),acc[0]); acc[1]=fmaf(ae,bhi(q.x),acc[1]);
      acc[2]=fmaf(ae,blo(q.y),acc[2]); acc[3]=fmaf(ae,bhi(q.y),acc[3]);
      acc[4]=fmaf(ae,blo(q.z),acc[4]); acc[5]=fmaf(ae,bhi(q.z),acc[5]);
      acc[6]=fmaf(ae,blo(q.w),acc[6]); acc[7]=fmaf(ae,bhi(q.w),acc[7]);
    }
  }
  s += __shfl_xor(s, 8, 64);
  s += __shfl_xor(s, 16, 64);
  s += __shfl_xor(s, 32, 64);
  float inv = 1.f/(s + 1e-16f);
  uint4 o;
  o.x = pk(acc[0]*inv, acc[1]*inv);
  o.y = pk(acc[2]*inv, acc[3]*inv);
  o.z = pk(acc[4]*inv, acc[5]*inv);
  o.w = pk(acc[6]*inv, acc[7]*inv);
  *(uint4*)(z16 + (size_t)ln*512 + hd*64 + cbo) = o;
}

// ---------------- final: mean over heads + bias + log_softmax ----------------
__global__ __launch_bounds__(256) void k_final(
    const float* __restrict__ acc, const float* __restrict__ b5,
    float* __restrict__ out, int N)
{
  int t = threadIdx.x;
  int node = blockIdx.x*4 + (t >> 6);
  if (node >= N) return;
  int tl = t & 63;
  float v = (tl < 40) ? acc[(size_t)node*40 + tl]*0.125f + b5[tl] : -1e30f;
  float m = v;
  #pragma unroll
  for (int o=32;o;o>>=1) m = fmaxf(m, __shfl_xor(m, o, 64));
  float ex = (tl < 40) ? __expf(v - m) : 0.f;
  float s = ex;
  #pragma unroll
  for (int o=32;o;o>>=1) s += __shfl_xor(s, o, 64);
  if (tl < 40) out[(size_t)node*40 + tl] = (v - m) - __logf(s);
}

extern "C" void kernel_launch(void* const* d_in, const int* in_sizes, int n_in,
                              void* d_out, int out_size, void* d_ws, size_t ws_size,
                              hipStream_t stream) {
  const float* x  = (const float*)d_in[0];
  const int*   ei = (const int*)d_in[1];
  const int N = in_sizes[0] / 128;
  const int E = in_sizes[1] / 2;
  const int* esrc = ei;
  const int* edst = ei + E;
  const float* W1 = (const float*)d_in[2];
  const float* as1= (const float*)d_in[3];
  const float* ad1= (const float*)d_in[4];
  const float* b1 = (const float*)d_in[5];
  const float* W2 = (const float*)d_in[6];
  const float* as2= (const float*)d_in[7];
  const float* ad2= (const float*)d_in[8];
  const float* b2 = (const float*)d_in[9];
  const float* W3 = (const float*)d_in[10];
  const float* as3= (const float*)d_in[11];
  const float* ad3= (const float*)d_in[12];
  const float* b3 = (const float*)d_in[13];
  const float* W4 = (const float*)d_in[14];
  const float* as4= (const float*)d_in[15];
  const float* ad4= (const float*)d_in[16];
  const float* b4 = (const float*)d_in[17];
  const float* W5 = (const float*)d_in[18];
  const float* as5= (const float*)d_in[19];
  const float* ad5= (const float*)d_in[20];
  const float* b5 = (const float*)d_in[21];

  char* p = (char*)d_ws;
  auto alloc = [&](size_t bytes)->void*{
    uintptr_t u = (uintptr_t)p;
    u = (u + 255) & ~(uintptr_t)255;
    void* r = (void*)u;
    p = (char*)u + bytes;
    return r;
  };
  const int Etot = E + N;
  const int NBLK = (Etot + 8191)/8192;
  const int L    = 512*NBLK;
  const int NB2  = (L + 255)/256;
  const int NG   = (N + 255)/256;

  int* off    = (int*)alloc((size_t)(N+1)*4);
  int* srcs   = (int*)alloc((size_t)Etot*4);
  int* hist   = (int*)alloc((size_t)L*4);
  int* hist2  = (int*)alloc((size_t)L*4);
  int* hb     = (int*)alloc((size_t)(NB2+1)*4);
  unsigned short* al_s16 = (unsigned short*)alloc((size_t)N*8*2);
  float* al_d = (float*)alloc((size_t)N*8*4);
  unsigned short* h16  = (unsigned short*)alloc((size_t)N*64*2);
  unsigned short* fB16 = (unsigned short*)alloc((size_t)N*64*2);
  float* featA= (float*)alloc((size_t)N*64*4);   // featA+featB contiguous -> z16 overlay
  float* featB= (float*)alloc((size_t)N*64*4);
  float* wsb  = (float*)alloc((size_t)8*64*4);
  float* wdb  = (float*)alloc((size_t)8*64*4);
  float* Wf   = (float*)alloc((size_t)512*40*4);
  float* out5 = (float*)alloc((size_t)N*40*4);
  unsigned short* zbuf = (unsigned short*)featA;  // 51.2MB >= 50000*512*2
  int2* bufA  = (int2*)featA;                     // sort scratch (dead before features)

  int gT = (N+63)/64, gA = (N+3)/4;
  int gA64 = (N+31)/32;
  int gAl = (N*8+255)/256;

  // CSR: atomic-free two-level bucket sort (self-loops synthesized)
  rs_hist1  <<<NBLK,256,0,stream>>>(edst, E, N, hist, NBLK, Etot);
  s_bsum    <<<NB2,256,0,stream>>>(hist, hb, L);
  k_bscan   <<<1,512,0,stream>>>(hb, hb, NB2);
  s_apply   <<<NB2,256,0,stream>>>(hist, hb, hist2, L);
  rs_scatter1<<<NBLK,256,0,stream>>>(esrc, edst, E, N, hist2, NBLK, bufA, Etot);
  rs_lvl2   <<<NG,256,0,stream>>>(bufA, hist2, NBLK, srcs, off, N, Etot);

  // Layer 1
  k_gemm<128,64,true><<<gT,256,0,stream>>>(x, W1, 64, 0, h16, N);
  k_al<<<gAl,256,0,stream>>>(h16, as1, ad1, al_s16, al_d, N*8);
  k_agg64<false><<<gA64,256,0,stream>>>(h16, al_s16, al_d, off, srcs, b1, featA, N, 1);

  // Layer 2
  k_gemm<64,64,true><<<gT,256,0,stream>>>(featA, W2, 64, 0, h16, N);
  k_al<<<gAl,256,0,stream>>>(h16, as2, ad2, al_s16, al_d, N*8);
  k_agg64<false><<<gA64,256,0,stream>>>(h16, al_s16, al_d, off, srcs, b2, featB, N, 1);

  // Layer 3
  k_gemm<64,64,true><<<gT,256,0,stream>>>(featB, W3, 64, 0, h16, N);
  k_al<<<gAl,256,0,stream>>>(h16, as3, ad3, al_s16, al_d, N*8);
  k_agg64<false><<<gA64,256,0,stream>>>(h16, al_s16, al_d, off, srcs, b3, featA, N, 1);

  // Layer 4 -> bf16 output (gathered by layer 5)
  k_gemm<64,64,true><<<gT,256,0,stream>>>(featA, W4, 64, 0, h16, N);
  k_al<<<gAl,256,0,stream>>>(h16, as4, ad4, al_s16, al_d, N*8);
  k_agg64<true><<<gA64,256,0,stream>>>(h16, al_s16, al_d, off, srcs, b4, fB16, N, 1);

  // Layer 5: folded attn logits; 2 chunks of bf16 z (overlaying featA+featB) then k_gemm5
  k_ws  <<<1,512,0,stream>>>(W5, as5, ad5, wsb, wdb);
  k_wf  <<<(512*40+255)/256,256,0,stream>>>(W5, Wf);
  k_al5b<<<gAl,256,0,stream>>>(fB16, wsb, wdb, al_s16, al_d, N*8);
  const int CH = 50000;
  for (int base = 0; base < N; base += CH){
    int cnt = (N - base < CH) ? (N - base) : CH;
    k_agg5z<<<(cnt+3)/4,256,0,stream>>>(fB16, al_s16, al_d, off, srcs, zbuf, base, cnt);
    k_gemm5<<<(cnt+63)/64,320,0,stream>>>(zbuf, Wf, out5, base, cnt);
  }

  // mean + bias + log_softmax
  k_final<<<gA,256,0,stream>>>(out5, b5, (float*)d_out, N);
}